// Round 6
// baseline (565.439 us; speedup 1.0000x reference)
//
#include <hip/hip_runtime.h>
#include <hip/hip_fp16.h>

typedef _Float16 half8 __attribute__((ext_vector_type(8)));
typedef _Float16 half4 __attribute__((ext_vector_type(4)));
typedef _Float16 half2v __attribute__((ext_vector_type(2)));
typedef float f32x4 __attribute__((ext_vector_type(4)));

#if __has_builtin(__builtin_amdgcn_fdot2)
#define FDOT2(a, b, c) __builtin_amdgcn_fdot2((a), (b), (c), false)
#else
static __device__ __forceinline__ float FDOT2(half2v a, half2v b, float c) {
  return (float)a[0] * (float)b[0] + (float)a[1] * (float)b[1] + c;
}
#endif
#define H2(v8, p) ((half2v){(v8)[2 * (p)], (v8)[2 * (p) + 1]})

// async global->LDS, 16B per lane; dest = lds base (wave-uniform) + lane*16
#define GLOAD_LDS16(gp, lp)                                                        \
  __builtin_amdgcn_global_load_lds(                                                \
      (const __attribute__((address_space(1))) void*)(gp),                         \
      (__attribute__((address_space(3))) void*)(lp), 16, 0, 0)

// 16-lane all-reduce via DPP rotate-accumulate: 4 VALU ops, no LDS pipe.
template <int CTRL>
__device__ __forceinline__ float dpp_add16(float x) {
  int y = __builtin_amdgcn_update_dpp(0, __float_as_int(x), CTRL, 0xf, 0xf, true);
  return x + __int_as_float(y);
}
__device__ __forceinline__ float rowsum16(float x) {
  x = dpp_add16<0x128>(x);  // row_ror:8
  x = dpp_add16<0x124>(x);  // row_ror:4
  x = dpp_add16<0x122>(x);  // row_ror:2
  x = dpp_add16<0x121>(x);  // row_ror:1
  return x;
}

// ---------------- mega prep kernel: x->f16 + weight transposes + f16 casts + deg hist ----------------
// WeF layout: lane-linear fragments WeF[g][lane][4]:
//   WeF[g*256 + l*4 + j] = We[(l>>4)*4 + j][g*16 + (l&15)]
// (conflict-free A-frag reads; validated r2: conflicts 11.6M -> 3.9M)
__global__ void prep_kernel(const float* __restrict__ x, _Float16* __restrict__ x16, int nx,
                            const float* __restrict__ Wl1, const float* __restrict__ Wr1,
                            _Float16* __restrict__ WlrT1,
                            const float* __restrict__ Wl2, const float* __restrict__ Wr2,
                            _Float16* __restrict__ WlrT2,
                            const float* __restrict__ Wd1, _Float16* __restrict__ WdT1,
                            const float* __restrict__ Wd2, _Float16* __restrict__ WdT2,
                            const float* __restrict__ We1, _Float16* __restrict__ WeF1,
                            const float* __restrict__ We2, _Float16* __restrict__ WeF2,
                            const float* __restrict__ att1, _Float16* __restrict__ att16_1,
                            const float* __restrict__ att2, _Float16* __restrict__ att16_2,
                            const int* __restrict__ dst0, int* __restrict__ deg, int E) {
  int i = blockIdx.x * 256 + threadIdx.x;
  if (i < nx) { x16[i] = (_Float16)x[i]; return; }
  i -= nx;
  if (i < 1024 * 128) {
    int n = i >> 7, k = i & 127;
    float v = (n < 512) ? Wl1[(size_t)k * 512 + n] : Wr1[(size_t)k * 512 + (n - 512)];
    WlrT1[i] = (_Float16)v; return;
  }
  i -= 1024 * 128;
  if (i < 1024 * 512) {
    int n = i >> 9, k = i & 511;
    float v = (n < 512) ? Wl2[(size_t)k * 512 + n] : Wr2[(size_t)k * 512 + (n - 512)];
    WlrT2[i] = (_Float16)v; return;
  }
  i -= 1024 * 512;
  if (i < 512 * 512) { int n = i >> 9, k = i & 511; WdT1[i] = (_Float16)Wd1[(size_t)k * 512 + n]; return; }
  i -= 512 * 512;
  if (i < 64 * 512)  { int n = i >> 9, k = i & 511; WdT2[i] = (_Float16)Wd2[(size_t)k * 64 + n]; return; }
  i -= 64 * 512;
  if (i < 512 * 16) {  // lane-linear fragment layout
    int j = i & 3, lrow = (i >> 2) & 63, g = i >> 8;
    int lq = lrow >> 4, lrr = lrow & 15;
    WeF1[i] = (_Float16)We1[(size_t)(lq * 4 + j) * 512 + g * 16 + lrr]; return;
  }
  i -= 512 * 16;
  if (i < 512 * 16) {
    int j = i & 3, lrow = (i >> 2) & 63, g = i >> 8;
    int lq = lrow >> 4, lrr = lrow & 15;
    WeF2[i] = (_Float16)We2[(size_t)(lq * 4 + j) * 512 + g * 16 + lrr]; return;
  }
  i -= 512 * 16;
  if (i < 512)       { att16_1[i] = (_Float16)att1[i]; return; }
  i -= 512;
  if (i < 512)       { att16_2[i] = (_Float16)att2[i]; return; }
  i -= 512;
  if (i < E)         { atomicAdd(&deg[dst0[i]], 1); return; }
}

// ---------------- CSR build ----------------
__global__ __launch_bounds__(1024) void scan_kernel(const int* __restrict__ deg, int* __restrict__ offs, int N) {
  __shared__ int part[1024];
  int t = threadIdx.x;
  int chunk = (N + 1023) / 1024;
  int b = t * chunk, e = min(b + chunk, N);
  int s = 0;
  for (int i = b; i < e; i++) s += deg[i] + 1;
  part[t] = s;
  __syncthreads();
  for (int off = 1; off < 1024; off <<= 1) {
    int v = (t >= off) ? part[t - off] : 0;
    __syncthreads();
    part[t] += v;
    __syncthreads();
  }
  int run = (t == 0) ? 0 : part[t - 1];
  for (int i = b; i < e; i++) { offs[i] = run; run += deg[i] + 1; }
  if (t == 1023) offs[N] = part[1023];
}

// scatter src + slot-ordered edge attr (f16) in one pass; self-loop slot marked, +64 slot pad
__global__ void csr_fill_kernel(const int* __restrict__ src0, const int* __restrict__ dst0,
                                const float* __restrict__ ea,
                                const int* __restrict__ offs, const int* __restrict__ deg,
                                int* __restrict__ cnt, int* __restrict__ csr_src,
                                _Float16* __restrict__ eas, int E, int N) {
  int i = blockIdx.x * 256 + threadIdx.x;
  if (i < 64) {
    if (i < 16) csr_src[E + N + i] = 0;
#pragma unroll
    for (int k = 0; k < 16; k++) eas[(size_t)(E + N + i) * 16 + k] = (_Float16)0.f;
  }
  if (i < E) {
    int d = dst0[i];
    int p = offs[d] + atomicAdd(&cnt[d], 1);
    csr_src[p] = src0[i];
    const float* s = ea + (size_t)i * 16;
    half8 h0, h1;
#pragma unroll
    for (int k = 0; k < 8; k++) { h0[k] = (_Float16)s[k]; h1[k] = (_Float16)s[k + 8]; }
    *(half8*)(eas + (size_t)p * 16) = h0;
    *(half8*)(eas + (size_t)p * 16 + 8) = h1;
  } else if (i < E + N) {
    int v = i - E;
    csr_src[offs[v] + deg[v]] = v;  // self-loop; attrs filled by loop_attr_kernel
  }
}

// self-loop attr = mean of real incoming slots (wave-per-node, coalesced)
__global__ void loop_attr_kernel(const int* __restrict__ offs, const int* __restrict__ deg,
                                 _Float16* __restrict__ eas, int N) {
  int wid = (blockIdx.x * 256 + threadIdx.x) >> 6;
  int l = threadIdx.x & 63;
  if (wid >= N) return;
  int b = offs[wid], dg = deg[wid];
  int k = l & 15, r = l >> 4;
  float s = 0.f;
  for (int j = r; j < dg; j += 4)
    s += (float)eas[(size_t)(b + j) * 16 + k];
  s += __shfl_xor(s, 16, 64);
  s += __shfl_xor(s, 32, 64);
  if (r == 0) eas[(size_t)(b + dg) * 16 + k] = (_Float16)(s / fmaxf((float)dg, 1.0f));
}

// ---------------- GEMM: C[M,Nfull] = A[M,K](f16) * BT[Nfull,K](f16) + bias ----------------
template <bool RELU, bool OUT_F32>
__global__ __launch_bounds__(256) void gemm_f16(const _Float16* __restrict__ A,
                                                const _Float16* __restrict__ BT,
                                                const float* __restrict__ biasA,
                                                const float* __restrict__ biasB,
                                                void* __restrict__ C,
                                                int M, int K, int Nfull, int ldc) {
  __shared__ _Float16 As[128 * 32];
  __shared__ _Float16 Bs[128 * 32];
  int t = threadIdx.x;
  int m0 = blockIdx.x * 128;
  int n0 = blockIdx.y * 128;
  int l = t & 63, w = t >> 6;
  int wm = w & 1, wn = w >> 1;
  int lr = l & 15, lq = l >> 4;

  f32x4 acc[4][4];
#pragma unroll
  for (int i = 0; i < 4; i++)
#pragma unroll
    for (int j = 0; j < 4; j++) acc[i][j] = (f32x4){0.f, 0.f, 0.f, 0.f};

  int r0 = w * 32 + (l >> 2);
  int cb = (l & 3) * 8;
  const _Float16* Ap = A + (size_t)(m0 + r0) * K + cb;
  const _Float16* Bp = BT + (size_t)(n0 + r0) * K + cb;
  _Float16* AsW = As + w * 32 * 32;
  _Float16* BsW = Bs + w * 32 * 32;

  for (int kk = 0; kk < K; kk += 32) {
    GLOAD_LDS16(Ap, AsW);
    GLOAD_LDS16(Ap + (size_t)16 * K, AsW + 16 * 32);
    GLOAD_LDS16(Bp, BsW);
    GLOAD_LDS16(Bp + (size_t)16 * K, BsW + 16 * 32);
    Ap += 32; Bp += 32;
    __syncthreads();
    half8 af[4], bf[4];
#pragma unroll
    for (int mi = 0; mi < 4; mi++) af[mi] = *(const half8*)&As[(wm * 64 + mi * 16 + lr) * 32 + lq * 8];
#pragma unroll
    for (int ni = 0; ni < 4; ni++) bf[ni] = *(const half8*)&Bs[(wn * 64 + ni * 16 + lr) * 32 + lq * 8];
#pragma unroll
    for (int mi = 0; mi < 4; mi++)
#pragma unroll
      for (int ni = 0; ni < 4; ni++)
        acc[mi][ni] = __builtin_amdgcn_mfma_f32_16x16x32_f16(af[mi], bf[ni], acc[mi][ni], 0, 0, 0);
    __syncthreads();
  }

#pragma unroll
  for (int ni = 0; ni < 4; ni++) {
    int col = n0 + wn * 64 + ni * 16 + lr;
    if (col >= Nfull) continue;
    float bv = (col < 512) ? biasA[col] : biasB[col - 512];
#pragma unroll
    for (int mi = 0; mi < 4; mi++) {
#pragma unroll
      for (int r = 0; r < 4; r++) {
        int row = m0 + wm * 64 + mi * 16 + lq * 4 + r;
        if (row >= M) continue;
        float v = acc[mi][ni][r] + bv;
        if (RELU) v = fmaxf(v, 0.f);
        if (OUT_F32) ((float*)C)[(size_t)row * ldc + col] = v;
        else ((_Float16*)C)[(size_t)row * ldc + col] = (_Float16)v;
      }
    }
  }
}

// ---------------- fused GATv2 edge pass (v9 = v4 structure + lane-linear WeFL) ----------------
// Round-17 synthesis: v4 (97.5us) is the best measured structure: 16-slot EF,
// 80KB LDS, 1-deep gather / 2-deep index pipeline, serial upd. Its one
// counter-indicted defect: 4-way bank conflict on WeFL A-frag reads (11.6M
// conflict cycles). The lane-linear WeF fix was validated in r2 (->3.9M) but
// never run on the v4 structure in isolation. v9 = exactly that.
// Occupancy lesson (r2-r5): achieved residency is ~5.5 waves/CU regardless of
// static cap (8 or 12); don't trade per-edge work for static occupancy.

__device__ __forceinline__ void upd(float p, half8 xs, float& m, float& den, float acc[8]) {
  float mn = fmaxf(m, p);
  float sc = __expf(m - mn);
  float al = __expf(p - mn);
  den = den * sc + al;
#pragma unroll
  for (int jj = 0; jj < 8; jj++) acc[jj] = acc[jj] * sc + al * (float)xs[jj];
  m = mn;
}

__global__ __launch_bounds__(256) void gat_fused_kernel(
    const _Float16* __restrict__ xlr,     // [Npad][1024]: 0..511 xl, 512..1023 xr
    const int* __restrict__ csr_src, const int* __restrict__ offs,
    const _Float16* __restrict__ eas,     // [EP+64][16] slot-ordered
    const _Float16* __restrict__ WeF,     // [32][64][4] lane-linear MFMA-A fragments
    const _Float16* __restrict__ att16,   // [4][128] f16
    const float* __restrict__ bias,
    _Float16* __restrict__ hout, int N) {
  __shared__ _Float16 WeFL[16 * 512];     // 16KB: A-fragments (lane-linear)
  __shared__ _Float16 EFs[4][16 * 512];   // 16KB/wave EF bounce (16 slots x 512 ch)
  int t = threadIdx.x;
  int l = t & 63;
  int w = t >> 6;
  int h = l >> 4;
  int c0 = l * 8;
  int lr = l & 15, lq = l >> 4;

  {
    const _Float16* gW = WeF + w * 512 + l * 8;
    _Float16* lW = WeFL + w * 512;
#pragma unroll
    for (int p = 0; p < 4; p++) GLOAD_LDS16(gW + p * 2048, lW + p * 2048);
  }
  __syncthreads();

  _Float16* EFw = &EFs[w][0];
  half8 attv = *(const half8*)(att16 + h * 128 + lr * 8);
  const half2v lk = {(_Float16)0.2f, (_Float16)0.2f};

  int wid = blockIdx.x * 4 + w;
  int nw = gridDim.x * 4;

  for (int v0 = wid; v0 < N; v0 += nw) {
    int v = __builtin_amdgcn_readfirstlane(v0);
    int b = offs[v], e2 = offs[v + 1];
    half8 xrv = *(const half8*)(xlr + (size_t)v * 1024 + 512 + c0);

    // quad 0 indices + data (prologue, once per node)
    int s0 = csr_src[b], s1 = csr_src[b + 1], s2 = csr_src[b + 2], s3 = csr_src[b + 3];
    half8 xs0 = *(const half8*)(xlr + (size_t)s0 * 1024 + c0);
    half8 xs1 = *(const half8*)(xlr + (size_t)s1 * 1024 + c0);
    half8 xs2 = *(const half8*)(xlr + (size_t)s2 * 1024 + c0);
    half8 xs3 = *(const half8*)(xlr + (size_t)s3 * 1024 + c0);
    int t0 = csr_src[b + 4], t1 = csr_src[b + 5], t2 = csr_src[b + 6], t3 = csr_src[b + 7];
    half4 bfrag = *(const half4*)(eas + (size_t)(b + lr) * 16 + lq * 4);

    float m = -1e30f, den = 0.f;
    float acc[8];
#pragma unroll
    for (int j = 0; j < 8; j++) acc[j] = 0.f;

    for (int cs = b; cs < e2; cs += 16) {
      // ---- EF MFMA phase for slots [cs, cs+16) ----
      // A-frag lane-linear: 8B/lane contiguous (conflict-free).
      // D: lane holds EF[ch=g*16+lq*4+r][slot=lr] -> f16 -> LDS, XOR-swizzled by slot.
#pragma unroll
      for (int g = 0; g < 32; g++) {
        half4 af = *(const half4*)(WeFL + g * 256 + l * 4);
        f32x4 d = __builtin_amdgcn_mfma_f32_16x16x16f16(af, bfrag, (f32x4){0.f, 0.f, 0.f, 0.f}, 0, 0, 0);
        half4 hd = {(_Float16)d[0], (_Float16)d[1], (_Float16)d[2], (_Float16)d[3]};
        int hi = (lr * 512 + g * 16 + lq * 4) ^ ((lr & 7) << 3);
        *(half4*)(EFw + hi) = hd;
      }
      // prefetch next chunk's ea fragment (eas padded by 64 slots)
      bfrag = *(const half4*)(eas + (size_t)(cs + 16 + lr) * 16 + lq * 4);

      int cse = min(cs + 16, e2);
      for (int j = cs; j < cse; j += 4) {
        // next quad's xs gathers (indices loaded last iteration)
        half8 nx0 = *(const half8*)(xlr + (size_t)t0 * 1024 + c0);
        half8 nx1 = *(const half8*)(xlr + (size_t)t1 * 1024 + c0);
        half8 nx2 = *(const half8*)(xlr + (size_t)t2 * 1024 + c0);
        half8 nx3 = *(const half8*)(xlr + (size_t)t3 * 1024 + c0);
        // indices for quad j+8 (2 ahead); csr_src padded +16
        int u0 = csr_src[j + 8], u1 = csr_src[j + 9], u2 = csr_src[j + 10], u3 = csr_src[j + 11];

        // EF rows for this quad (conflict-free swizzled b128)
        int si = j - cs;
        half8 ef0 = *(const half8*)(EFw + (((si    ) * 512 + l * 8) ^ (((si    ) & 7) << 3)));
        half8 ef1 = *(const half8*)(EFw + (((si + 1) * 512 + l * 8) ^ (((si + 1) & 7) << 3)));
        half8 ef2 = *(const half8*)(EFw + (((si + 2) * 512 + l * 8) ^ (((si + 2) & 7) << 3)));
        half8 ef3 = *(const half8*)(EFw + (((si + 3) * 512 + l * 8) ^ (((si + 3) & 7) << 3)));

        float p0 = 0.f, p1 = 0.f, p2 = 0.f, p3 = 0.f;
#pragma unroll
        for (int p = 0; p < 4; p++) {
          half2v xrp = H2(xrv, p);
          half2v ap = H2(attv, p);
          half2v v0v = H2(xs0, p) + xrp + H2(ef0, p);
          half2v v1v = H2(xs1, p) + xrp + H2(ef1, p);
          half2v v2v = H2(xs2, p) + xrp + H2(ef2, p);
          half2v v3v = H2(xs3, p) + xrp + H2(ef3, p);
          v0v = __builtin_elementwise_max(v0v, v0v * lk);
          v1v = __builtin_elementwise_max(v1v, v1v * lk);
          v2v = __builtin_elementwise_max(v2v, v2v * lk);
          v3v = __builtin_elementwise_max(v3v, v3v * lk);
          p0 = FDOT2(v0v, ap, p0);
          p1 = FDOT2(v1v, ap, p1);
          p2 = FDOT2(v2v, ap, p2);
          p3 = FDOT2(v3v, ap, p3);
        }
        p0 = rowsum16(p0); p1 = rowsum16(p1); p2 = rowsum16(p2); p3 = rowsum16(p3);

        upd(p0, xs0, m, den, acc);
        if (j + 1 < e2) upd(p1, xs1, m, den, acc);
        if (j + 2 < e2) upd(p2, xs2, m, den, acc);
        if (j + 3 < e2) upd(p3, xs3, m, den, acc);

        // rotate pipeline
        xs0 = nx0; xs1 = nx1; xs2 = nx2; xs3 = nx3;
        t0 = u0; t1 = u1; t2 = u2; t3 = u3;
      }
    }
    float rd = 1.f / (den + 1e-16f);
    half8 o;
#pragma unroll
    for (int jj = 0; jj < 8; jj++) o[jj] = (_Float16)(fmaf(acc[jj], rd, bias[c0 + jj]));
    *(half8*)(hout + (size_t)v * 512 + c0) = o;
  }
}

// ---------------- launcher ----------------

extern "C" void kernel_launch(void* const* d_in, const int* in_sizes, int n_in,
                              void* d_out, int out_size, void* d_ws, size_t ws_size,
                              hipStream_t stream) {
  (void)n_in; (void)out_size; (void)ws_size;
  const float* x    = (const float*)d_in[0];
  const int*   ei   = (const int*)d_in[1];
  const float* ea   = (const float*)d_in[2];
  const float* Wl1  = (const float*)d_in[3];
  const float* bl1  = (const float*)d_in[4];
  const float* Wr1  = (const float*)d_in[5];
  const float* br1  = (const float*)d_in[6];
  const float* We1  = (const float*)d_in[7];
  const float* att1 = (const float*)d_in[8];
  const float* bias1= (const float*)d_in[9];
  const float* Wl2  = (const float*)d_in[10];
  const float* bl2  = (const float*)d_in[11];
  const float* Wr2  = (const float*)d_in[12];
  const float* br2  = (const float*)d_in[13];
  const float* We2  = (const float*)d_in[14];
  const float* att2 = (const float*)d_in[15];
  const float* bias2= (const float*)d_in[16];
  const float* Wd1  = (const float*)d_in[17];
  const float* bd1  = (const float*)d_in[18];
  const float* Wd2  = (const float*)d_in[19];
  const float* bd2  = (const float*)d_in[20];

  const int N = in_sizes[0] / 128;
  const int E = in_sizes[1] / 2;
  const int EP = E + N;
  const int Npad = (N + 127) & ~127;
  const int* src0 = ei;
  const int* dst0 = ei + E;

  char* ws = (char*)d_ws;
  size_t off = 0;
  auto alloc = [&](size_t bytes) -> void* {
    void* p = ws + off;
    off += (bytes + 255) & ~(size_t)255;
    return p;
  };

  int*   deg    = (int*)alloc((size_t)N * 8);
  int*   cnt    = deg + N;
  int*   offs   = (int*)alloc(((size_t)N + 1) * 4);
  int*   csr_src= (int*)alloc(((size_t)EP + 16) * 4);
  _Float16* eas = (_Float16*)alloc(((size_t)EP + 64) * 16 * 2);
  _Float16* x16   = (_Float16*)alloc((size_t)Npad * 128 * 2);
  _Float16* xlr16 = (_Float16*)alloc((size_t)Npad * 1024 * 2);
  _Float16* h16   = (_Float16*)alloc((size_t)Npad * 512 * 2);
  _Float16* WlrT1 = (_Float16*)alloc(1024 * 128 * 2);
  _Float16* WlrT2 = (_Float16*)alloc(1024 * 512 * 2);
  _Float16* WdT1  = (_Float16*)alloc(512 * 512 * 2);
  _Float16* WdT2  = (_Float16*)alloc(128 * 512 * 2);
  _Float16* WeF1  = (_Float16*)alloc(16 * 512 * 2);
  _Float16* WeF2  = (_Float16*)alloc(16 * 512 * 2);
  _Float16* att16_1 = (_Float16*)alloc(512 * 2);
  _Float16* att16_2 = (_Float16*)alloc(512 * 2);
  _Float16* t16   = xlr16;  // decoder hidden reuses xlr buffer (dead by then)

  hipMemsetAsync(deg, 0, (size_t)N * 8, stream);

  // mega prep (also does the degree histogram)
  int nx = N * 128;
  int prep_base = nx + 1024 * 128 + 1024 * 512 + 512 * 512 + 64 * 512
                + 512 * 16 + 512 * 16 + 512 + 512;
  int prep_total = prep_base + E;
  prep_kernel<<<(prep_total + 255) / 256, 256, 0, stream>>>(
      x, x16, nx, Wl1, Wr1, WlrT1, Wl2, Wr2, WlrT2,
      Wd1, WdT1, Wd2, WdT2, We1, WeF1, We2, WeF2,
      att1, att16_1, att2, att16_2, dst0, deg, E);

  // CSR build (csr_fill also writes slot-ordered edge attrs)
  int g;
  scan_kernel<<<1, 1024, 0, stream>>>(deg, offs, N);
  g = (EP + 255) / 256;
  csr_fill_kernel<<<g, 256, 0, stream>>>(src0, dst0, ea, offs, deg, cnt, csr_src, eas, E, N);
  g = (N * 64 + 255) / 256;
  loop_attr_kernel<<<g, 256, 0, stream>>>(offs, deg, eas, N);

  dim3 gb(256);
  dim3 ggm((N + 127) / 128, 8);
  dim3 ggd((N + 127) / 128, 4);
  dim3 ggo((N + 127) / 128, 1);

  const int FGRID = 2048;

  // ---- GAT layer 1 ----
  gemm_f16<false, false><<<ggm, gb, 0, stream>>>(x16, WlrT1, bl1, br1, xlr16, N, 128, 1024, 1024);
  gat_fused_kernel<<<FGRID, 256, 0, stream>>>(xlr16, csr_src, offs, eas, WeF1, att16_1, bias1, h16, N);

  // ---- GAT layer 2 ----
  gemm_f16<false, false><<<ggm, gb, 0, stream>>>(h16, WlrT2, bl2, br2, xlr16, N, 512, 1024, 1024);
  gat_fused_kernel<<<FGRID, 256, 0, stream>>>(xlr16, csr_src, offs, eas, WeF2, att16_2, bias2, h16, N);

  // ---- decoder ----
  gemm_f16<true, false><<<ggd, gb, 0, stream>>>(h16, WdT1, bd1, bd1, t16, N, 512, 512, 512);
  gemm_f16<false, true><<<ggo, gb, 0, stream>>>(t16, WdT2, bd2, bd2, d_out, N, 512, 64, 64);
}

// Round 7
// 560.556 us; speedup vs baseline: 1.0087x; 1.0087x over previous
//
#include <hip/hip_runtime.h>
#include <hip/hip_fp16.h>

typedef _Float16 half8 __attribute__((ext_vector_type(8)));
typedef _Float16 half4 __attribute__((ext_vector_type(4)));
typedef _Float16 half2v __attribute__((ext_vector_type(2)));
typedef float f32x4 __attribute__((ext_vector_type(4)));

#if __has_builtin(__builtin_amdgcn_fdot2)
#define FDOT2(a, b, c) __builtin_amdgcn_fdot2((a), (b), (c), false)
#else
static __device__ __forceinline__ float FDOT2(half2v a, half2v b, float c) {
  return (float)a[0] * (float)b[0] + (float)a[1] * (float)b[1] + c;
}
#endif
#define H2(v8, p) ((half2v){(v8)[2 * (p)], (v8)[2 * (p) + 1]})

// async global->LDS, 16B per lane; dest = lds base (wave-uniform) + lane*16
#define GLOAD_LDS16(gp, lp)                                                        \
  __builtin_amdgcn_global_load_lds(                                                \
      (const __attribute__((address_space(1))) void*)(gp),                         \
      (__attribute__((address_space(3))) void*)(lp), 16, 0, 0)

// 16-lane all-reduce via DPP rotate-accumulate: 4 VALU ops, no LDS pipe.
template <int CTRL>
__device__ __forceinline__ float dpp_add16(float x) {
  int y = __builtin_amdgcn_update_dpp(0, __float_as_int(x), CTRL, 0xf, 0xf, true);
  return x + __int_as_float(y);
}
__device__ __forceinline__ float rowsum16(float x) {
  x = dpp_add16<0x128>(x);  // row_ror:8
  x = dpp_add16<0x124>(x);  // row_ror:4
  x = dpp_add16<0x122>(x);  // row_ror:2
  x = dpp_add16<0x121>(x);  // row_ror:1
  return x;
}

// ---------------- mega prep kernel: x->f16 + weight transposes + f16 casts + deg hist ----------------
// WeF layout: v4's [32 groups][16 ch][16 k] fragment layout.
// NOTE (r6 lesson): the "conflict-free" lane-linear relayout (r5/v9) perturbed
// regalloc (VGPR 116->132, crossing the 128 waves-halve cliff) and cost +35%.
// Keep the v4 layout; its 4-way A-frag conflict is the cheaper evil.
__global__ void prep_kernel(const float* __restrict__ x, _Float16* __restrict__ x16, int nx,
                            const float* __restrict__ Wl1, const float* __restrict__ Wr1,
                            _Float16* __restrict__ WlrT1,
                            const float* __restrict__ Wl2, const float* __restrict__ Wr2,
                            _Float16* __restrict__ WlrT2,
                            const float* __restrict__ Wd1, _Float16* __restrict__ WdT1,
                            const float* __restrict__ Wd2, _Float16* __restrict__ WdT2,
                            const float* __restrict__ We1, _Float16* __restrict__ WeF1,
                            const float* __restrict__ We2, _Float16* __restrict__ WeF2,
                            const float* __restrict__ att1, _Float16* __restrict__ att16_1,
                            const float* __restrict__ att2, _Float16* __restrict__ att16_2,
                            const int* __restrict__ dst0, int* __restrict__ deg, int E) {
  int i = blockIdx.x * 256 + threadIdx.x;
  if (i < nx) { x16[i] = (_Float16)x[i]; return; }
  i -= nx;
  if (i < 1024 * 128) {
    int n = i >> 7, k = i & 127;
    float v = (n < 512) ? Wl1[(size_t)k * 512 + n] : Wr1[(size_t)k * 512 + (n - 512)];
    WlrT1[i] = (_Float16)v; return;
  }
  i -= 1024 * 128;
  if (i < 1024 * 512) {
    int n = i >> 9, k = i & 511;
    float v = (n < 512) ? Wl2[(size_t)k * 512 + n] : Wr2[(size_t)k * 512 + (n - 512)];
    WlrT2[i] = (_Float16)v; return;
  }
  i -= 1024 * 512;
  if (i < 512 * 512) { int n = i >> 9, k = i & 511; WdT1[i] = (_Float16)Wd1[(size_t)k * 512 + n]; return; }
  i -= 512 * 512;
  if (i < 64 * 512)  { int n = i >> 9, k = i & 511; WdT2[i] = (_Float16)Wd2[(size_t)k * 64 + n]; return; }
  i -= 64 * 512;
  if (i < 512 * 16) {  // WeF1[g][c][k] = We1[k][g*16+c]  (v4 layout)
    int k = i & 15, c = (i >> 4) & 15, g = i >> 8;
    WeF1[i] = (_Float16)We1[(size_t)k * 512 + g * 16 + c]; return;
  }
  i -= 512 * 16;
  if (i < 512 * 16) {
    int k = i & 15, c = (i >> 4) & 15, g = i >> 8;
    WeF2[i] = (_Float16)We2[(size_t)k * 512 + g * 16 + c]; return;
  }
  i -= 512 * 16;
  if (i < 512)       { att16_1[i] = (_Float16)att1[i]; return; }
  i -= 512;
  if (i < 512)       { att16_2[i] = (_Float16)att2[i]; return; }
  i -= 512;
  if (i < E)         { atomicAdd(&deg[dst0[i]], 1); return; }
}

// ---------------- CSR build ----------------
__global__ __launch_bounds__(1024) void scan_kernel(const int* __restrict__ deg, int* __restrict__ offs, int N) {
  __shared__ int part[1024];
  int t = threadIdx.x;
  int chunk = (N + 1023) / 1024;
  int b = t * chunk, e = min(b + chunk, N);
  int s = 0;
  for (int i = b; i < e; i++) s += deg[i] + 1;
  part[t] = s;
  __syncthreads();
  for (int off = 1; off < 1024; off <<= 1) {
    int v = (t >= off) ? part[t - off] : 0;
    __syncthreads();
    part[t] += v;
    __syncthreads();
  }
  int run = (t == 0) ? 0 : part[t - 1];
  for (int i = b; i < e; i++) { offs[i] = run; run += deg[i] + 1; }
  if (t == 1023) offs[N] = part[1023];
}

// scatter src + slot-ordered edge attr (f16) in one pass; self-loop slot marked, +64 slot pad
__global__ void csr_fill_kernel(const int* __restrict__ src0, const int* __restrict__ dst0,
                                const float* __restrict__ ea,
                                const int* __restrict__ offs, const int* __restrict__ deg,
                                int* __restrict__ cnt, int* __restrict__ csr_src,
                                _Float16* __restrict__ eas, int E, int N) {
  int i = blockIdx.x * 256 + threadIdx.x;
  if (i < 64) {
    if (i < 16) csr_src[E + N + i] = 0;
#pragma unroll
    for (int k = 0; k < 16; k++) eas[(size_t)(E + N + i) * 16 + k] = (_Float16)0.f;
  }
  if (i < E) {
    int d = dst0[i];
    int p = offs[d] + atomicAdd(&cnt[d], 1);
    csr_src[p] = src0[i];
    const float* s = ea + (size_t)i * 16;
    half8 h0, h1;
#pragma unroll
    for (int k = 0; k < 8; k++) { h0[k] = (_Float16)s[k]; h1[k] = (_Float16)s[k + 8]; }
    *(half8*)(eas + (size_t)p * 16) = h0;
    *(half8*)(eas + (size_t)p * 16 + 8) = h1;
  } else if (i < E + N) {
    int v = i - E;
    csr_src[offs[v] + deg[v]] = v;  // self-loop; attrs filled by loop_attr_kernel
  }
}

// self-loop attr = mean of real incoming slots (wave-per-node, coalesced)
__global__ void loop_attr_kernel(const int* __restrict__ offs, const int* __restrict__ deg,
                                 _Float16* __restrict__ eas, int N) {
  int wid = (blockIdx.x * 256 + threadIdx.x) >> 6;
  int l = threadIdx.x & 63;
  if (wid >= N) return;
  int b = offs[wid], dg = deg[wid];
  int k = l & 15, r = l >> 4;
  float s = 0.f;
  for (int j = r; j < dg; j += 4)
    s += (float)eas[(size_t)(b + j) * 16 + k];
  s += __shfl_xor(s, 16, 64);
  s += __shfl_xor(s, 32, 64);
  if (r == 0) eas[(size_t)(b + dg) * 16 + k] = (_Float16)(s / fmaxf((float)dg, 1.0f));
}

// ---------------- GEMM: C[M,Nfull] = A[M,K](f16) * BT[Nfull,K](f16) + bias ----------------
template <bool RELU, bool OUT_F32>
__global__ __launch_bounds__(256) void gemm_f16(const _Float16* __restrict__ A,
                                                const _Float16* __restrict__ BT,
                                                const float* __restrict__ biasA,
                                                const float* __restrict__ biasB,
                                                void* __restrict__ C,
                                                int M, int K, int Nfull, int ldc) {
  __shared__ _Float16 As[128 * 32];
  __shared__ _Float16 Bs[128 * 32];
  int t = threadIdx.x;
  int m0 = blockIdx.x * 128;
  int n0 = blockIdx.y * 128;
  int l = t & 63, w = t >> 6;
  int wm = w & 1, wn = w >> 1;
  int lr = l & 15, lq = l >> 4;

  f32x4 acc[4][4];
#pragma unroll
  for (int i = 0; i < 4; i++)
#pragma unroll
    for (int j = 0; j < 4; j++) acc[i][j] = (f32x4){0.f, 0.f, 0.f, 0.f};

  int r0 = w * 32 + (l >> 2);
  int cb = (l & 3) * 8;
  const _Float16* Ap = A + (size_t)(m0 + r0) * K + cb;
  const _Float16* Bp = BT + (size_t)(n0 + r0) * K + cb;
  _Float16* AsW = As + w * 32 * 32;
  _Float16* BsW = Bs + w * 32 * 32;

  for (int kk = 0; kk < K; kk += 32) {
    GLOAD_LDS16(Ap, AsW);
    GLOAD_LDS16(Ap + (size_t)16 * K, AsW + 16 * 32);
    GLOAD_LDS16(Bp, BsW);
    GLOAD_LDS16(Bp + (size_t)16 * K, BsW + 16 * 32);
    Ap += 32; Bp += 32;
    __syncthreads();
    half8 af[4], bf[4];
#pragma unroll
    for (int mi = 0; mi < 4; mi++) af[mi] = *(const half8*)&As[(wm * 64 + mi * 16 + lr) * 32 + lq * 8];
#pragma unroll
    for (int ni = 0; ni < 4; ni++) bf[ni] = *(const half8*)&Bs[(wn * 64 + ni * 16 + lr) * 32 + lq * 8];
#pragma unroll
    for (int mi = 0; mi < 4; mi++)
#pragma unroll
      for (int ni = 0; ni < 4; ni++)
        acc[mi][ni] = __builtin_amdgcn_mfma_f32_16x16x32_f16(af[mi], bf[ni], acc[mi][ni], 0, 0, 0);
    __syncthreads();
  }

#pragma unroll
  for (int ni = 0; ni < 4; ni++) {
    int col = n0 + wn * 64 + ni * 16 + lr;
    if (col >= Nfull) continue;
    float bv = (col < 512) ? biasA[col] : biasB[col - 512];
#pragma unroll
    for (int mi = 0; mi < 4; mi++) {
#pragma unroll
      for (int r = 0; r < 4; r++) {
        int row = m0 + wm * 64 + mi * 16 + lq * 4 + r;
        if (row >= M) continue;
        float v = acc[mi][ni][r] + bv;
        if (RELU) v = fmaxf(v, 0.f);
        if (OUT_F32) ((float*)C)[(size_t)row * ldc + col] = v;
        else ((_Float16*)C)[(size_t)row * ldc + col] = (_Float16)v;
      }
    }
  }
}

// ---------------- fused GATv2 edge pass (v10 = exact v4 + batched masked softmax) ----------------
// Round-18: v4 (97.5us, VGPR 116, occ 17%) remains the best measured build.
// Law from r2-r6: any variant whose VGPR drifts >128 falls off the waves-halve
// cliff (occ ~9%, +35%); launch_bounds min-waves overshoots (r4: asked<=170,
// got 84 + spills) -- so pressure is controlled by construction only.
// v10's single change: the 4 serial upd() calls (8 exps, 64 chained acc-FMAs,
// 4-deep serial rescale = longest dep chain per quad) -> one batched masked
// update (5 exps, 40 FMAs, 1 rescale). Liveness +4 scalars only.

__global__ __launch_bounds__(256) void gat_fused_kernel(
    const _Float16* __restrict__ xlr,     // [Npad][1024]: 0..511 xl, 512..1023 xr
    const int* __restrict__ csr_src, const int* __restrict__ offs,
    const _Float16* __restrict__ eas,     // [EP+64][16] slot-ordered
    const _Float16* __restrict__ WeF,     // [32][16][16] MFMA-A fragment layout (v4)
    const _Float16* __restrict__ att16,   // [4][128] f16
    const float* __restrict__ bias,
    _Float16* __restrict__ hout, int N) {
  __shared__ _Float16 WeFL[16 * 512];     // 16KB: A-fragments
  __shared__ _Float16 EFs[4][16 * 512];   // 16KB/wave EF bounce buffer
  int t = threadIdx.x;
  int l = t & 63;
  int w = t >> 6;
  int h = l >> 4;
  int c0 = l * 8;
  int lr = l & 15, lq = l >> 4;

  {
    const _Float16* gW = WeF + w * 512 + l * 8;
    _Float16* lW = WeFL + w * 512;
#pragma unroll
    for (int p = 0; p < 4; p++) GLOAD_LDS16(gW + p * 2048, lW + p * 2048);
  }
  __syncthreads();

  _Float16* EFw = &EFs[w][0];
  half8 attv = *(const half8*)(att16 + h * 128 + lr * 8);
  const half2v lk = {(_Float16)0.2f, (_Float16)0.2f};

  int wid = blockIdx.x * 4 + w;
  int nw = gridDim.x * 4;

  for (int v0 = wid; v0 < N; v0 += nw) {
    int v = __builtin_amdgcn_readfirstlane(v0);
    int b = offs[v], e2 = offs[v + 1];
    half8 xrv = *(const half8*)(xlr + (size_t)v * 1024 + 512 + c0);

    // quad 0 indices + data (prologue, once per node)
    int s0 = csr_src[b], s1 = csr_src[b + 1], s2 = csr_src[b + 2], s3 = csr_src[b + 3];
    half8 xs0 = *(const half8*)(xlr + (size_t)s0 * 1024 + c0);
    half8 xs1 = *(const half8*)(xlr + (size_t)s1 * 1024 + c0);
    half8 xs2 = *(const half8*)(xlr + (size_t)s2 * 1024 + c0);
    half8 xs3 = *(const half8*)(xlr + (size_t)s3 * 1024 + c0);
    int t0 = csr_src[b + 4], t1 = csr_src[b + 5], t2 = csr_src[b + 6], t3 = csr_src[b + 7];
    half4 bfrag = *(const half4*)(eas + (size_t)(b + lr) * 16 + lq * 4);

    float m = -1e30f, den = 0.f;
    float acc[8];
#pragma unroll
    for (int j = 0; j < 8; j++) acc[j] = 0.f;

    for (int cs = b; cs < e2; cs += 16) {
      // ---- EF MFMA phase for slots [cs, cs+16) ----
      // A-frag: lane = We[k=lq*4+j][ch=g*16+lr]; B-frag: lane = ea[slot=lr][k=lq*4+j]
      // D: lane holds EF[ch=g*16+lq*4+r][slot=lr] -> f16 -> LDS (XOR-swizzled by slot)
#pragma unroll
      for (int g = 0; g < 32; g++) {
        half4 af = *(const half4*)(WeFL + g * 256 + lr * 16 + lq * 4);
        f32x4 d = __builtin_amdgcn_mfma_f32_16x16x16f16(af, bfrag, (f32x4){0.f, 0.f, 0.f, 0.f}, 0, 0, 0);
        half4 hd = {(_Float16)d[0], (_Float16)d[1], (_Float16)d[2], (_Float16)d[3]};
        int hi = (lr * 512 + g * 16 + lq * 4) ^ ((lr & 7) << 3);
        *(half4*)(EFw + hi) = hd;
      }
      // prefetch next chunk's ea fragment (safe: eas padded by 64 slots)
      bfrag = *(const half4*)(eas + (size_t)(cs + 16 + lr) * 16 + lq * 4);

      int cse = min(cs + 16, e2);
      for (int j = cs; j < cse; j += 4) {
        // next quad's xs gathers (indices loaded last iteration)
        half8 nx0 = *(const half8*)(xlr + (size_t)t0 * 1024 + c0);
        half8 nx1 = *(const half8*)(xlr + (size_t)t1 * 1024 + c0);
        half8 nx2 = *(const half8*)(xlr + (size_t)t2 * 1024 + c0);
        half8 nx3 = *(const half8*)(xlr + (size_t)t3 * 1024 + c0);
        // indices for quad j+8 (2 ahead); csr_src padded +16
        int u0 = csr_src[j + 8], u1 = csr_src[j + 9], u2 = csr_src[j + 10], u3 = csr_src[j + 11];

        // EF rows for this quad (conflict-free swizzled b128)
        int si = j - cs;
        half8 ef0 = *(const half8*)(EFw + (((si    ) * 512 + l * 8) ^ (((si    ) & 7) << 3)));
        half8 ef1 = *(const half8*)(EFw + (((si + 1) * 512 + l * 8) ^ (((si + 1) & 7) << 3)));
        half8 ef2 = *(const half8*)(EFw + (((si + 2) * 512 + l * 8) ^ (((si + 2) & 7) << 3)));
        half8 ef3 = *(const half8*)(EFw + (((si + 3) * 512 + l * 8) ^ (((si + 3) & 7) << 3)));

        float p0 = 0.f, p1 = 0.f, p2 = 0.f, p3 = 0.f;
#pragma unroll
        for (int p = 0; p < 4; p++) {
          half2v xrp = H2(xrv, p);
          half2v ap = H2(attv, p);
          half2v v0v = H2(xs0, p) + xrp + H2(ef0, p);
          half2v v1v = H2(xs1, p) + xrp + H2(ef1, p);
          half2v v2v = H2(xs2, p) + xrp + H2(ef2, p);
          half2v v3v = H2(xs3, p) + xrp + H2(ef3, p);
          v0v = __builtin_elementwise_max(v0v, v0v * lk);
          v1v = __builtin_elementwise_max(v1v, v1v * lk);
          v2v = __builtin_elementwise_max(v2v, v2v * lk);
          v3v = __builtin_elementwise_max(v3v, v3v * lk);
          p0 = FDOT2(v0v, ap, p0);
          p1 = FDOT2(v1v, ap, p1);
          p2 = FDOT2(v2v, ap, p2);
          p3 = FDOT2(v3v, ap, p3);
        }
        p0 = rowsum16(p0); p1 = rowsum16(p1); p2 = rowsum16(p2); p3 = rowsum16(p3);

        // ---- batched masked online-softmax update (v10) ----
        if (j + 1 >= e2) p1 = -1e30f;
        if (j + 2 >= e2) p2 = -1e30f;
        if (j + 3 >= e2) p3 = -1e30f;
        float q = fmaxf(fmaxf(fmaxf(p0, p1), fmaxf(p2, p3)), m);
        float sc = __expf(m - q);
        float a0 = __expf(p0 - q), a1 = __expf(p1 - q);
        float a2 = __expf(p2 - q), a3 = __expf(p3 - q);
        den = fmaf(den, sc, (a0 + a1) + (a2 + a3));
#pragma unroll
        for (int jj = 0; jj < 8; jj++) {
          float w0 = fmaf(a0, (float)xs0[jj], a1 * (float)xs1[jj]);
          float w1 = fmaf(a2, (float)xs2[jj], a3 * (float)xs3[jj]);
          acc[jj] = fmaf(acc[jj], sc, w0 + w1);
        }
        m = q;

        // rotate pipeline
        xs0 = nx0; xs1 = nx1; xs2 = nx2; xs3 = nx3;
        t0 = u0; t1 = u1; t2 = u2; t3 = u3;
      }
    }
    float rd = 1.f / (den + 1e-16f);
    half8 o;
#pragma unroll
    for (int jj = 0; jj < 8; jj++) o[jj] = (_Float16)(fmaf(acc[jj], rd, bias[c0 + jj]));
    *(half8*)(hout + (size_t)v * 512 + c0) = o;
  }
}

// ---------------- launcher ----------------

extern "C" void kernel_launch(void* const* d_in, const int* in_sizes, int n_in,
                              void* d_out, int out_size, void* d_ws, size_t ws_size,
                              hipStream_t stream) {
  (void)n_in; (void)out_size; (void)ws_size;
  const float* x    = (const float*)d_in[0];
  const int*   ei   = (const int*)d_in[1];
  const float* ea   = (const float*)d_in[2];
  const float* Wl1  = (const float*)d_in[3];
  const float* bl1  = (const float*)d_in[4];
  const float* Wr1  = (const float*)d_in[5];
  const float* br1  = (const float*)d_in[6];
  const float* We1  = (const float*)d_in[7];
  const float* att1 = (const float*)d_in[8];
  const float* bias1= (const float*)d_in[9];
  const float* Wl2  = (const float*)d_in[10];
  const float* bl2  = (const float*)d_in[11];
  const float* Wr2  = (const float*)d_in[12];
  const float* br2  = (const float*)d_in[13];
  const float* We2  = (const float*)d_in[14];
  const float* att2 = (const float*)d_in[15];
  const float* bias2= (const float*)d_in[16];
  const float* Wd1  = (const float*)d_in[17];
  const float* bd1  = (const float*)d_in[18];
  const float* Wd2  = (const float*)d_in[19];
  const float* bd2  = (const float*)d_in[20];

  const int N = in_sizes[0] / 128;
  const int E = in_sizes[1] / 2;
  const int EP = E + N;
  const int Npad = (N + 127) & ~127;
  const int* src0 = ei;
  const int* dst0 = ei + E;

  char* ws = (char*)d_ws;
  size_t off = 0;
  auto alloc = [&](size_t bytes) -> void* {
    void* p = ws + off;
    off += (bytes + 255) & ~(size_t)255;
    return p;
  };

  int*   deg    = (int*)alloc((size_t)N * 8);
  int*   cnt    = deg + N;
  int*   offs   = (int*)alloc(((size_t)N + 1) * 4);
  int*   csr_src= (int*)alloc(((size_t)EP + 16) * 4);
  _Float16* eas = (_Float16*)alloc(((size_t)EP + 64) * 16 * 2);
  _Float16* x16   = (_Float16*)alloc((size_t)Npad * 128 * 2);
  _Float16* xlr16 = (_Float16*)alloc((size_t)Npad * 1024 * 2);
  _Float16* h16   = (_Float16*)alloc((size_t)Npad * 512 * 2);
  _Float16* WlrT1 = (_Float16*)alloc(1024 * 128 * 2);
  _Float16* WlrT2 = (_Float16*)alloc(1024 * 512 * 2);
  _Float16* WdT1  = (_Float16*)alloc(512 * 512 * 2);
  _Float16* WdT2  = (_Float16*)alloc(128 * 512 * 2);
  _Float16* WeF1  = (_Float16*)alloc(16 * 512 * 2);
  _Float16* WeF2  = (_Float16*)alloc(16 * 512 * 2);
  _Float16* att16_1 = (_Float16*)alloc(512 * 2);
  _Float16* att16_2 = (_Float16*)alloc(512 * 2);
  _Float16* t16   = xlr16;  // decoder hidden reuses xlr buffer (dead by then)

  hipMemsetAsync(deg, 0, (size_t)N * 8, stream);

  // mega prep (also does the degree histogram)
  int nx = N * 128;
  int prep_base = nx + 1024 * 128 + 1024 * 512 + 512 * 512 + 64 * 512
                + 512 * 16 + 512 * 16 + 512 + 512;
  int prep_total = prep_base + E;
  prep_kernel<<<(prep_total + 255) / 256, 256, 0, stream>>>(
      x, x16, nx, Wl1, Wr1, WlrT1, Wl2, Wr2, WlrT2,
      Wd1, WdT1, Wd2, WdT2, We1, WeF1, We2, WeF2,
      att1, att16_1, att2, att16_2, dst0, deg, E);

  // CSR build (csr_fill also writes slot-ordered edge attrs)
  int g;
  scan_kernel<<<1, 1024, 0, stream>>>(deg, offs, N);
  g = (EP + 255) / 256;
  csr_fill_kernel<<<g, 256, 0, stream>>>(src0, dst0, ea, offs, deg, cnt, csr_src, eas, E, N);
  g = (N * 64 + 255) / 256;
  loop_attr_kernel<<<g, 256, 0, stream>>>(offs, deg, eas, N);

  dim3 gb(256);
  dim3 ggm((N + 127) / 128, 8);
  dim3 ggd((N + 127) / 128, 4);
  dim3 ggo((N + 127) / 128, 1);

  const int FGRID = 2048;

  // ---- GAT layer 1 ----
  gemm_f16<false, false><<<ggm, gb, 0, stream>>>(x16, WlrT1, bl1, br1, xlr16, N, 128, 1024, 1024);
  gat_fused_kernel<<<FGRID, 256, 0, stream>>>(xlr16, csr_src, offs, eas, WeF1, att16_1, bias1, h16, N);

  // ---- GAT layer 2 ----
  gemm_f16<false, false><<<ggm, gb, 0, stream>>>(h16, WlrT2, bl2, br2, xlr16, N, 512, 1024, 1024);
  gat_fused_kernel<<<FGRID, 256, 0, stream>>>(xlr16, csr_src, offs, eas, WeF2, att16_2, bias2, h16, N);

  // ---- decoder ----
  gemm_f16<true, false><<<ggd, gb, 0, stream>>>(h16, WdT1, bd1, bd1, t16, N, 512, 512, 512);
  gemm_f16<false, true><<<ggo, gb, 0, stream>>>(t16, WdT2, bd2, bd2, d_out, N, 512, 64, 64);
}

// Round 8
// 503.059 us; speedup vs baseline: 1.1240x; 1.1143x over previous
//
#include <hip/hip_runtime.h>
#include <hip/hip_fp16.h>

typedef _Float16 half8 __attribute__((ext_vector_type(8)));
typedef _Float16 half4 __attribute__((ext_vector_type(4)));
typedef _Float16 half2v __attribute__((ext_vector_type(2)));
typedef float f32x4 __attribute__((ext_vector_type(4)));

#if __has_builtin(__builtin_amdgcn_fdot2)
#define FDOT2(a, b, c) __builtin_amdgcn_fdot2((a), (b), (c), false)
#else
static __device__ __forceinline__ float FDOT2(half2v a, half2v b, float c) {
  return (float)a[0] * (float)b[0] + (float)a[1] * (float)b[1] + c;
}
#endif
#define H2(v8, p) ((half2v){(v8)[2 * (p)], (v8)[2 * (p) + 1]})

// async global->LDS, 16B per lane; dest = lds base (wave-uniform) + lane*16
#define GLOAD_LDS16(gp, lp)                                                        \
  __builtin_amdgcn_global_load_lds(                                                \
      (const __attribute__((address_space(1))) void*)(gp),                         \
      (__attribute__((address_space(3))) void*)(lp), 16, 0, 0)

// 16-lane all-reduce via DPP rotate-accumulate: 4 VALU ops, no LDS pipe.
template <int CTRL>
__device__ __forceinline__ float dpp_add16(float x) {
  int y = __builtin_amdgcn_update_dpp(0, __float_as_int(x), CTRL, 0xf, 0xf, true);
  return x + __int_as_float(y);
}
__device__ __forceinline__ float rowsum16(float x) {
  x = dpp_add16<0x128>(x);  // row_ror:8
  x = dpp_add16<0x124>(x);  // row_ror:4
  x = dpp_add16<0x122>(x);  // row_ror:2
  x = dpp_add16<0x121>(x);  // row_ror:1
  return x;
}

// ---------------- mega prep kernel ----------------
// WeF layout: v4's [32 groups][16 ch][16 k] (r6 lesson: lane-linear relayout
// perturbs gat regalloc over the 128-VGPR cliff; keep v4).
__global__ void prep_kernel(const float* __restrict__ x, _Float16* __restrict__ x16, int nx,
                            const float* __restrict__ Wl1, const float* __restrict__ Wr1,
                            _Float16* __restrict__ WlrT1,
                            const float* __restrict__ Wl2, const float* __restrict__ Wr2,
                            _Float16* __restrict__ WlrT2,
                            const float* __restrict__ Wd1, _Float16* __restrict__ WdT1,
                            const float* __restrict__ Wd2, _Float16* __restrict__ WdT2,
                            const float* __restrict__ We1, _Float16* __restrict__ WeF1,
                            const float* __restrict__ We2, _Float16* __restrict__ WeF2,
                            const float* __restrict__ att1, _Float16* __restrict__ att16_1,
                            const float* __restrict__ att2, _Float16* __restrict__ att16_2,
                            const int* __restrict__ dst0, int* __restrict__ deg, int E) {
  int i = blockIdx.x * 256 + threadIdx.x;
  if (i < nx) { x16[i] = (_Float16)x[i]; return; }
  i -= nx;
  if (i < 1024 * 128) {
    int n = i >> 7, k = i & 127;
    float v = (n < 512) ? Wl1[(size_t)k * 512 + n] : Wr1[(size_t)k * 512 + (n - 512)];
    WlrT1[i] = (_Float16)v; return;
  }
  i -= 1024 * 128;
  if (i < 1024 * 512) {
    int n = i >> 9, k = i & 511;
    float v = (n < 512) ? Wl2[(size_t)k * 512 + n] : Wr2[(size_t)k * 512 + (n - 512)];
    WlrT2[i] = (_Float16)v; return;
  }
  i -= 1024 * 512;
  if (i < 512 * 512) { int n = i >> 9, k = i & 511; WdT1[i] = (_Float16)Wd1[(size_t)k * 512 + n]; return; }
  i -= 512 * 512;
  if (i < 64 * 512)  { int n = i >> 9, k = i & 511; WdT2[i] = (_Float16)Wd2[(size_t)k * 64 + n]; return; }
  i -= 64 * 512;
  if (i < 512 * 16) {  // WeF1[g][c][k] = We1[k][g*16+c]  (v4 layout)
    int k = i & 15, c = (i >> 4) & 15, g = i >> 8;
    WeF1[i] = (_Float16)We1[(size_t)k * 512 + g * 16 + c]; return;
  }
  i -= 512 * 16;
  if (i < 512 * 16) {
    int k = i & 15, c = (i >> 4) & 15, g = i >> 8;
    WeF2[i] = (_Float16)We2[(size_t)k * 512 + g * 16 + c]; return;
  }
  i -= 512 * 16;
  if (i < 512)       { att16_1[i] = (_Float16)att1[i]; return; }
  i -= 512;
  if (i < 512)       { att16_2[i] = (_Float16)att2[i]; return; }
  i -= 512;
  if (i < E)         { atomicAdd(&deg[dst0[i]], 1); return; }
}

// ---------------- CSR build ----------------
__global__ __launch_bounds__(1024) void scan_kernel(const int* __restrict__ deg, int* __restrict__ offs, int N) {
  __shared__ int part[1024];
  int t = threadIdx.x;
  int chunk = (N + 1023) / 1024;
  int b = t * chunk, e = min(b + chunk, N);
  int s = 0;
  for (int i = b; i < e; i++) s += deg[i] + 1;
  part[t] = s;
  __syncthreads();
  for (int off = 1; off < 1024; off <<= 1) {
    int v = (t >= off) ? part[t - off] : 0;
    __syncthreads();
    part[t] += v;
    __syncthreads();
  }
  int run = (t == 0) ? 0 : part[t - 1];
  for (int i = b; i < e; i++) { offs[i] = run; run += deg[i] + 1; }
  if (t == 1023) offs[N] = part[1023];
}

// scatter src + slot-ordered edge attr (f16) in one pass; pads zeroed 64 slots
__global__ void csr_fill_kernel(const int* __restrict__ src0, const int* __restrict__ dst0,
                                const float* __restrict__ ea,
                                const int* __restrict__ offs, const int* __restrict__ deg,
                                int* __restrict__ cnt, int* __restrict__ csr_src,
                                _Float16* __restrict__ eas, int E, int N) {
  int i = blockIdx.x * 256 + threadIdx.x;
  if (i < 64) {
    if (i < 16) csr_src[E + N + i] = 0;
#pragma unroll
    for (int k = 0; k < 16; k++) eas[(size_t)(E + N + i) * 16 + k] = (_Float16)0.f;
  }
  if (i < E) {
    int d = dst0[i];
    int p = offs[d] + atomicAdd(&cnt[d], 1);
    csr_src[p] = src0[i];
    const float* s = ea + (size_t)i * 16;
    half8 h0, h1;
#pragma unroll
    for (int k = 0; k < 8; k++) { h0[k] = (_Float16)s[k]; h1[k] = (_Float16)s[k + 8]; }
    *(half8*)(eas + (size_t)p * 16) = h0;
    *(half8*)(eas + (size_t)p * 16 + 8) = h1;
  } else if (i < E + N) {
    int v = i - E;
    csr_src[offs[v] + deg[v]] = v;  // self-loop; attrs filled by loop_attr_kernel
  }
}

// self-loop attr = mean of real incoming slots (wave-per-node, coalesced)
__global__ void loop_attr_kernel(const int* __restrict__ offs, const int* __restrict__ deg,
                                 _Float16* __restrict__ eas, int N) {
  int wid = (blockIdx.x * 256 + threadIdx.x) >> 6;
  int l = threadIdx.x & 63;
  if (wid >= N) return;
  int b = offs[wid], dg = deg[wid];
  int k = l & 15, r = l >> 4;
  float s = 0.f;
  for (int j = r; j < dg; j += 4)
    s += (float)eas[(size_t)(b + j) * 16 + k];
  s += __shfl_xor(s, 16, 64);
  s += __shfl_xor(s, 32, 64);
  if (r == 0) eas[(size_t)(b + dg) * 16 + k] = (_Float16)(s / fmaxf((float)dg, 1.0f));
}

// ---------------- GEMM: [M,Nfull] = A[M,K]*BT[Nfull,K] + bias, split outputs ----------------
// r8 change: cols 0..511 -> CA[row*ldc+col], cols 512..1023 -> CB[row*ldc+col-512].
// Epilogue-only change (regalloc-insensitive); enables the xl/xr split that
// shrinks the gat gather working set 41MB -> 20.5MB (fits 32MB aggregate L2).
template <bool RELU, bool OUT_F32>
__global__ __launch_bounds__(256) void gemm_f16(const _Float16* __restrict__ A,
                                                const _Float16* __restrict__ BT,
                                                const float* __restrict__ biasA,
                                                const float* __restrict__ biasB,
                                                void* __restrict__ CA,
                                                void* __restrict__ CB,
                                                int M, int K, int Nfull, int ldc) {
  __shared__ _Float16 As[128 * 32];
  __shared__ _Float16 Bs[128 * 32];
  int t = threadIdx.x;
  int m0 = blockIdx.x * 128;
  int n0 = blockIdx.y * 128;
  int l = t & 63, w = t >> 6;
  int wm = w & 1, wn = w >> 1;
  int lr = l & 15, lq = l >> 4;

  f32x4 acc[4][4];
#pragma unroll
  for (int i = 0; i < 4; i++)
#pragma unroll
    for (int j = 0; j < 4; j++) acc[i][j] = (f32x4){0.f, 0.f, 0.f, 0.f};

  int r0 = w * 32 + (l >> 2);
  int cb = (l & 3) * 8;
  const _Float16* Ap = A + (size_t)(m0 + r0) * K + cb;
  const _Float16* Bp = BT + (size_t)(n0 + r0) * K + cb;
  _Float16* AsW = As + w * 32 * 32;
  _Float16* BsW = Bs + w * 32 * 32;

  for (int kk = 0; kk < K; kk += 32) {
    GLOAD_LDS16(Ap, AsW);
    GLOAD_LDS16(Ap + (size_t)16 * K, AsW + 16 * 32);
    GLOAD_LDS16(Bp, BsW);
    GLOAD_LDS16(Bp + (size_t)16 * K, BsW + 16 * 32);
    Ap += 32; Bp += 32;
    __syncthreads();
    half8 af[4], bf[4];
#pragma unroll
    for (int mi = 0; mi < 4; mi++) af[mi] = *(const half8*)&As[(wm * 64 + mi * 16 + lr) * 32 + lq * 8];
#pragma unroll
    for (int ni = 0; ni < 4; ni++) bf[ni] = *(const half8*)&Bs[(wn * 64 + ni * 16 + lr) * 32 + lq * 8];
#pragma unroll
    for (int mi = 0; mi < 4; mi++)
#pragma unroll
      for (int ni = 0; ni < 4; ni++)
        acc[mi][ni] = __builtin_amdgcn_mfma_f32_16x16x32_f16(af[mi], bf[ni], acc[mi][ni], 0, 0, 0);
    __syncthreads();
  }

#pragma unroll
  for (int ni = 0; ni < 4; ni++) {
    int col = n0 + wn * 64 + ni * 16 + lr;
    if (col >= Nfull) continue;
    float bv = (col < 512) ? biasA[col] : biasB[col - 512];
    void* Cx = (col < 512) ? CA : CB;
    int cc = (col < 512) ? col : col - 512;
#pragma unroll
    for (int mi = 0; mi < 4; mi++) {
#pragma unroll
      for (int r = 0; r < 4; r++) {
        int row = m0 + wm * 64 + mi * 16 + lq * 4 + r;
        if (row >= M) continue;
        float v = acc[mi][ni][r] + bv;
        if (RELU) v = fmaxf(v, 0.f);
        if (OUT_F32) ((float*)Cx)[(size_t)row * ldc + cc] = v;
        else ((_Float16*)Cx)[(size_t)row * ldc + cc] = (_Float16)v;
      }
    }
  }
}

// ---------------- fused GATv2 edge pass (v11 = byte-exact r1/v4 loop, xl/xr split) ----------------
// r2-r7 law: the v4 inner loop at VGPR 116 is the only build under the 128-VGPR
// waves-halve cliff; every structural edit (conflict-fix relayout, batched
// softmax, deeper pipeline, slot resize) crossed it and cost 30-55%. The loop
// below is the r1 97.5us body verbatim; only the x addressing changed
// (xlr[v*1024] -> xl/xr[v*512]) to make the gather working set L2-resident.

__device__ __forceinline__ void upd(float p, half8 xs, float& m, float& den, float acc[8]) {
  float mn = fmaxf(m, p);
  float sc = __expf(m - mn);
  float al = __expf(p - mn);
  den = den * sc + al;
#pragma unroll
  for (int jj = 0; jj < 8; jj++) acc[jj] = acc[jj] * sc + al * (float)xs[jj];
  m = mn;
}

__global__ __launch_bounds__(256) void gat_fused_kernel(
    const _Float16* __restrict__ xl,      // [Npad][512] source transforms
    const _Float16* __restrict__ xr,      // [Npad][512] target transforms
    const int* __restrict__ csr_src, const int* __restrict__ offs,
    const _Float16* __restrict__ eas,     // [EP+64][16] slot-ordered
    const _Float16* __restrict__ WeF,     // [32][16][16] MFMA-A fragment layout (v4)
    const _Float16* __restrict__ att16,   // [4][128] f16
    const float* __restrict__ bias,
    _Float16* __restrict__ hout, int N) {
  __shared__ _Float16 WeFL[16 * 512];     // 16KB: A-fragments
  __shared__ _Float16 EFs[4][16 * 512];   // 16KB/wave EF bounce buffer
  int t = threadIdx.x;
  int l = t & 63;
  int w = t >> 6;
  int h = l >> 4;
  int c0 = l * 8;
  int lr = l & 15, lq = l >> 4;

  {
    const _Float16* gW = WeF + w * 512 + l * 8;
    _Float16* lW = WeFL + w * 512;
#pragma unroll
    for (int p = 0; p < 4; p++) GLOAD_LDS16(gW + p * 2048, lW + p * 2048);
  }
  __syncthreads();

  _Float16* EFw = &EFs[w][0];
  half8 attv = *(const half8*)(att16 + h * 128 + lr * 8);
  const half2v lk = {(_Float16)0.2f, (_Float16)0.2f};

  int wid = blockIdx.x * 4 + w;
  int nw = gridDim.x * 4;

  for (int v0 = wid; v0 < N; v0 += nw) {
    int v = __builtin_amdgcn_readfirstlane(v0);
    int b = offs[v], e2 = offs[v + 1];
    half8 xrv = *(const half8*)(xr + (size_t)v * 512 + c0);

    // quad 0 indices + data (prologue, once per node)
    int s0 = csr_src[b], s1 = csr_src[b + 1], s2 = csr_src[b + 2], s3 = csr_src[b + 3];
    half8 xs0 = *(const half8*)(xl + (size_t)s0 * 512 + c0);
    half8 xs1 = *(const half8*)(xl + (size_t)s1 * 512 + c0);
    half8 xs2 = *(const half8*)(xl + (size_t)s2 * 512 + c0);
    half8 xs3 = *(const half8*)(xl + (size_t)s3 * 512 + c0);
    int t0 = csr_src[b + 4], t1 = csr_src[b + 5], t2 = csr_src[b + 6], t3 = csr_src[b + 7];
    half4 bfrag = *(const half4*)(eas + (size_t)(b + lr) * 16 + lq * 4);

    float m = -1e30f, den = 0.f;
    float acc[8];
#pragma unroll
    for (int j = 0; j < 8; j++) acc[j] = 0.f;

    for (int cs = b; cs < e2; cs += 16) {
      // ---- EF MFMA phase for slots [cs, cs+16) ----
#pragma unroll
      for (int g = 0; g < 32; g++) {
        half4 af = *(const half4*)(WeFL + g * 256 + lr * 16 + lq * 4);
        f32x4 d = __builtin_amdgcn_mfma_f32_16x16x16f16(af, bfrag, (f32x4){0.f, 0.f, 0.f, 0.f}, 0, 0, 0);
        half4 hd = {(_Float16)d[0], (_Float16)d[1], (_Float16)d[2], (_Float16)d[3]};
        int hi = (lr * 512 + g * 16 + lq * 4) ^ ((lr & 7) << 3);
        *(half4*)(EFw + hi) = hd;
      }
      // prefetch next chunk's ea fragment (eas padded by 64 slots)
      bfrag = *(const half4*)(eas + (size_t)(cs + 16 + lr) * 16 + lq * 4);

      int cse = min(cs + 16, e2);
      for (int j = cs; j < cse; j += 4) {
        // next quad's xs gathers (indices loaded last iteration)
        half8 nx0 = *(const half8*)(xl + (size_t)t0 * 512 + c0);
        half8 nx1 = *(const half8*)(xl + (size_t)t1 * 512 + c0);
        half8 nx2 = *(const half8*)(xl + (size_t)t2 * 512 + c0);
        half8 nx3 = *(const half8*)(xl + (size_t)t3 * 512 + c0);
        // indices for quad j+8 (2 ahead); csr_src padded +16
        int u0 = csr_src[j + 8], u1 = csr_src[j + 9], u2 = csr_src[j + 10], u3 = csr_src[j + 11];

        // EF rows for this quad (conflict-free swizzled b128)
        int si = j - cs;
        half8 ef0 = *(const half8*)(EFw + (((si    ) * 512 + l * 8) ^ (((si    ) & 7) << 3)));
        half8 ef1 = *(const half8*)(EFw + (((si + 1) * 512 + l * 8) ^ (((si + 1) & 7) << 3)));
        half8 ef2 = *(const half8*)(EFw + (((si + 2) * 512 + l * 8) ^ (((si + 2) & 7) << 3)));
        half8 ef3 = *(const half8*)(EFw + (((si + 3) * 512 + l * 8) ^ (((si + 3) & 7) << 3)));

        float p0 = 0.f, p1 = 0.f, p2 = 0.f, p3 = 0.f;
#pragma unroll
        for (int p = 0; p < 4; p++) {
          half2v xrp = H2(xrv, p);
          half2v ap = H2(attv, p);
          half2v v0v = H2(xs0, p) + xrp + H2(ef0, p);
          half2v v1v = H2(xs1, p) + xrp + H2(ef1, p);
          half2v v2v = H2(xs2, p) + xrp + H2(ef2, p);
          half2v v3v = H2(xs3, p) + xrp + H2(ef3, p);
          v0v = __builtin_elementwise_max(v0v, v0v * lk);
          v1v = __builtin_elementwise_max(v1v, v1v * lk);
          v2v = __builtin_elementwise_max(v2v, v2v * lk);
          v3v = __builtin_elementwise_max(v3v, v3v * lk);
          p0 = FDOT2(v0v, ap, p0);
          p1 = FDOT2(v1v, ap, p1);
          p2 = FDOT2(v2v, ap, p2);
          p3 = FDOT2(v3v, ap, p3);
        }
        p0 = rowsum16(p0); p1 = rowsum16(p1); p2 = rowsum16(p2); p3 = rowsum16(p3);

        upd(p0, xs0, m, den, acc);
        if (j + 1 < e2) upd(p1, xs1, m, den, acc);
        if (j + 2 < e2) upd(p2, xs2, m, den, acc);
        if (j + 3 < e2) upd(p3, xs3, m, den, acc);

        // rotate pipeline
        xs0 = nx0; xs1 = nx1; xs2 = nx2; xs3 = nx3;
        t0 = u0; t1 = u1; t2 = u2; t3 = u3;
      }
    }
    float rd = 1.f / (den + 1e-16f);
    half8 o;
#pragma unroll
    for (int jj = 0; jj < 8; jj++) o[jj] = (_Float16)(fmaf(acc[jj], rd, bias[c0 + jj]));
    *(half8*)(hout + (size_t)v * 512 + c0) = o;
  }
}

// ---------------- launcher ----------------

extern "C" void kernel_launch(void* const* d_in, const int* in_sizes, int n_in,
                              void* d_out, int out_size, void* d_ws, size_t ws_size,
                              hipStream_t stream) {
  (void)n_in; (void)out_size; (void)ws_size;
  const float* x    = (const float*)d_in[0];
  const int*   ei   = (const int*)d_in[1];
  const float* ea   = (const float*)d_in[2];
  const float* Wl1  = (const float*)d_in[3];
  const float* bl1  = (const float*)d_in[4];
  const float* Wr1  = (const float*)d_in[5];
  const float* br1  = (const float*)d_in[6];
  const float* We1  = (const float*)d_in[7];
  const float* att1 = (const float*)d_in[8];
  const float* bias1= (const float*)d_in[9];
  const float* Wl2  = (const float*)d_in[10];
  const float* bl2  = (const float*)d_in[11];
  const float* Wr2  = (const float*)d_in[12];
  const float* br2  = (const float*)d_in[13];
  const float* We2  = (const float*)d_in[14];
  const float* att2 = (const float*)d_in[15];
  const float* bias2= (const float*)d_in[16];
  const float* Wd1  = (const float*)d_in[17];
  const float* bd1  = (const float*)d_in[18];
  const float* Wd2  = (const float*)d_in[19];
  const float* bd2  = (const float*)d_in[20];

  const int N = in_sizes[0] / 128;
  const int E = in_sizes[1] / 2;
  const int EP = E + N;
  const int Npad = (N + 127) & ~127;
  const int* src0 = ei;
  const int* dst0 = ei + E;

  char* ws = (char*)d_ws;
  size_t off = 0;
  auto alloc = [&](size_t bytes) -> void* {
    void* p = ws + off;
    off += (bytes + 255) & ~(size_t)255;
    return p;
  };

  int*   deg    = (int*)alloc((size_t)N * 8);
  int*   cnt    = deg + N;
  int*   offs   = (int*)alloc(((size_t)N + 1) * 4);
  int*   csr_src= (int*)alloc(((size_t)EP + 16) * 4);
  _Float16* eas = (_Float16*)alloc(((size_t)EP + 64) * 16 * 2);
  _Float16* x16   = (_Float16*)alloc((size_t)Npad * 128 * 2);
  _Float16* xl16  = (_Float16*)alloc((size_t)Npad * 512 * 2);
  _Float16* xr16  = (_Float16*)alloc((size_t)Npad * 512 * 2);
  _Float16* h16   = (_Float16*)alloc((size_t)Npad * 512 * 2);
  _Float16* WlrT1 = (_Float16*)alloc(1024 * 128 * 2);
  _Float16* WlrT2 = (_Float16*)alloc(1024 * 512 * 2);
  _Float16* WdT1  = (_Float16*)alloc(512 * 512 * 2);
  _Float16* WdT2  = (_Float16*)alloc(128 * 512 * 2);
  _Float16* WeF1  = (_Float16*)alloc(16 * 512 * 2);
  _Float16* WeF2  = (_Float16*)alloc(16 * 512 * 2);
  _Float16* att16_1 = (_Float16*)alloc(512 * 2);
  _Float16* att16_2 = (_Float16*)alloc(512 * 2);
  _Float16* t16   = xl16;  // decoder hidden reuses xl buffer (dead by then)

  hipMemsetAsync(deg, 0, (size_t)N * 8, stream);

  // mega prep (also does the degree histogram)
  int nx = N * 128;
  int prep_base = nx + 1024 * 128 + 1024 * 512 + 512 * 512 + 64 * 512
                + 512 * 16 + 512 * 16 + 512 + 512;
  int prep_total = prep_base + E;
  prep_kernel<<<(prep_total + 255) / 256, 256, 0, stream>>>(
      x, x16, nx, Wl1, Wr1, WlrT1, Wl2, Wr2, WlrT2,
      Wd1, WdT1, Wd2, WdT2, We1, WeF1, We2, WeF2,
      att1, att16_1, att2, att16_2, dst0, deg, E);

  // CSR build (csr_fill also writes slot-ordered edge attrs)
  int g;
  scan_kernel<<<1, 1024, 0, stream>>>(deg, offs, N);
  g = (EP + 255) / 256;
  csr_fill_kernel<<<g, 256, 0, stream>>>(src0, dst0, ea, offs, deg, cnt, csr_src, eas, E, N);
  g = (N * 64 + 255) / 256;
  loop_attr_kernel<<<g, 256, 0, stream>>>(offs, deg, eas, N);

  dim3 gb(256);
  dim3 ggm((N + 127) / 128, 8);
  dim3 ggd((N + 127) / 128, 4);
  dim3 ggo((N + 127) / 128, 1);

  const int FGRID = 2048;

  // ---- GAT layer 1 ----
  gemm_f16<false, false><<<ggm, gb, 0, stream>>>(x16, WlrT1, bl1, br1, xl16, xr16, N, 128, 1024, 512);
  gat_fused_kernel<<<FGRID, 256, 0, stream>>>(xl16, xr16, csr_src, offs, eas, WeF1, att16_1, bias1, h16, N);

  // ---- GAT layer 2 ----
  gemm_f16<false, false><<<ggm, gb, 0, stream>>>(h16, WlrT2, bl2, br2, xl16, xr16, N, 512, 1024, 512);
  gat_fused_kernel<<<FGRID, 256, 0, stream>>>(xl16, xr16, csr_src, offs, eas, WeF2, att16_2, bias2, h16, N);

  // ---- decoder ----
  gemm_f16<true, false><<<ggd, gb, 0, stream>>>(h16, WdT1, bd1, bd1, t16, t16, N, 512, 512, 512);
  gemm_f16<false, true><<<ggo, gb, 0, stream>>>(t16, WdT2, bd2, bd2, d_out, d_out, N, 512, 64, 64);
}

// Round 11
// 490.278 us; speedup vs baseline: 1.1533x; 1.0261x over previous
//
#include <hip/hip_runtime.h>
#include <hip/hip_fp16.h>

typedef _Float16 half8 __attribute__((ext_vector_type(8)));
typedef _Float16 half4 __attribute__((ext_vector_type(4)));
typedef _Float16 half2v __attribute__((ext_vector_type(2)));
typedef float f32x4 __attribute__((ext_vector_type(4)));

#if __has_builtin(__builtin_amdgcn_fdot2)
#define FDOT2(a, b, c) __builtin_amdgcn_fdot2((a), (b), (c), false)
#else
static __device__ __forceinline__ float FDOT2(half2v a, half2v b, float c) {
  return (float)a[0] * (float)b[0] + (float)a[1] * (float)b[1] + c;
}
#endif
#define H2(v8, p) ((half2v){(v8)[2 * (p)], (v8)[2 * (p) + 1]})

// async global->LDS, 16B per lane; dest = lds base (wave-uniform) + lane*16
#define GLOAD_LDS16(gp, lp)                                                        \
  __builtin_amdgcn_global_load_lds(                                                \
      (const __attribute__((address_space(1))) void*)(gp),                         \
      (__attribute__((address_space(3))) void*)(lp), 16, 0, 0)

// 16-lane all-reduce via DPP rotate-accumulate: 4 VALU ops, no LDS pipe.
template <int CTRL>
__device__ __forceinline__ float dpp_add16(float x) {
  int y = __builtin_amdgcn_update_dpp(0, __float_as_int(x), CTRL, 0xf, 0xf, true);
  return x + __int_as_float(y);
}
__device__ __forceinline__ float rowsum16(float x) {
  x = dpp_add16<0x128>(x);  // row_ror:8
  x = dpp_add16<0x124>(x);  // row_ror:4
  x = dpp_add16<0x122>(x);  // row_ror:2
  x = dpp_add16<0x121>(x);  // row_ror:1
  return x;
}

// XCD-aware bijective block remap (m204): cluster blocks sharing an A-panel on
// one XCD so its 4MB L2 holds ~20 A-panels (2.5MB) + the whole B panel (<=1MB).
__device__ __forceinline__ int xcd_remap(int bid, int nwg) {
  int xcd = bid & 7, idx = bid >> 3;
  int q8 = nwg >> 3, r8 = nwg & 7;
  return (xcd < r8) ? (xcd * (q8 + 1) + idx)
                    : (r8 * (q8 + 1) + (xcd - r8) * q8 + idx);
}

// ---------------- mega prep kernel ----------------
// WeF layout: v4's [32 groups][16 ch][16 k] (r6 lesson: lane-linear relayout
// perturbs gat regalloc over the 128-VGPR cliff; keep v4).
__global__ void prep_kernel(const float* __restrict__ x, _Float16* __restrict__ x16, int nx,
                            const float* __restrict__ Wl1, const float* __restrict__ Wr1,
                            _Float16* __restrict__ WlrT1,
                            const float* __restrict__ Wl2, const float* __restrict__ Wr2,
                            _Float16* __restrict__ WlrT2,
                            const float* __restrict__ Wd1, _Float16* __restrict__ WdT1,
                            const float* __restrict__ Wd2, _Float16* __restrict__ WdT2,
                            const float* __restrict__ We1, _Float16* __restrict__ WeF1,
                            const float* __restrict__ We2, _Float16* __restrict__ WeF2,
                            const float* __restrict__ att1, _Float16* __restrict__ att16_1,
                            const float* __restrict__ att2, _Float16* __restrict__ att16_2,
                            const int* __restrict__ dst0, int* __restrict__ deg, int E) {
  int i = blockIdx.x * 256 + threadIdx.x;
  if (i < nx) { x16[i] = (_Float16)x[i]; return; }
  i -= nx;
  if (i < 1024 * 128) {
    int n = i >> 7, k = i & 127;
    float v = (n < 512) ? Wl1[(size_t)k * 512 + n] : Wr1[(size_t)k * 512 + (n - 512)];
    WlrT1[i] = (_Float16)v; return;
  }
  i -= 1024 * 128;
  if (i < 1024 * 512) {
    int n = i >> 9, k = i & 511;
    float v = (n < 512) ? Wl2[(size_t)k * 512 + n] : Wr2[(size_t)k * 512 + (n - 512)];
    WlrT2[i] = (_Float16)v; return;
  }
  i -= 1024 * 512;
  if (i < 512 * 512) { int n = i >> 9, k = i & 511; WdT1[i] = (_Float16)Wd1[(size_t)k * 512 + n]; return; }
  i -= 512 * 512;
  if (i < 64 * 512)  { int n = i >> 9, k = i & 511; WdT2[i] = (_Float16)Wd2[(size_t)k * 64 + n]; return; }
  i -= 64 * 512;
  if (i < 512 * 16) {  // WeF1[g][c][k] = We1[k][g*16+c]  (v4 layout)
    int k = i & 15, c = (i >> 4) & 15, g = i >> 8;
    WeF1[i] = (_Float16)We1[(size_t)k * 512 + g * 16 + c]; return;
  }
  i -= 512 * 16;
  if (i < 512 * 16) {
    int k = i & 15, c = (i >> 4) & 15, g = i >> 8;
    WeF2[i] = (_Float16)We2[(size_t)k * 512 + g * 16 + c]; return;
  }
  i -= 512 * 16;
  if (i < 512)       { att16_1[i] = (_Float16)att1[i]; return; }
  i -= 512;
  if (i < 512)       { att16_2[i] = (_Float16)att2[i]; return; }
  i -= 512;
  if (i < E)         { atomicAdd(&deg[dst0[i]], 1); return; }
}

// ---------------- CSR build ----------------
__global__ __launch_bounds__(1024) void scan_kernel(const int* __restrict__ deg, int* __restrict__ offs, int N) {
  __shared__ int part[1024];
  int t = threadIdx.x;
  int chunk = (N + 1023) / 1024;
  int b = t * chunk, e = min(b + chunk, N);
  int s = 0;
  for (int i = b; i < e; i++) s += deg[i] + 1;
  part[t] = s;
  __syncthreads();
  for (int off = 1; off < 1024; off <<= 1) {
    int v = (t >= off) ? part[t - off] : 0;
    __syncthreads();
    part[t] += v;
    __syncthreads();
  }
  int run = (t == 0) ? 0 : part[t - 1];
  for (int i = b; i < e; i++) { offs[i] = run; run += deg[i] + 1; }
  if (t == 1023) offs[N] = part[1023];
}

// scatter src + slot-ordered edge attr (f16) in one pass; pads zeroed 64 slots
__global__ void csr_fill_kernel(const int* __restrict__ src0, const int* __restrict__ dst0,
                                const float* __restrict__ ea,
                                const int* __restrict__ offs, const int* __restrict__ deg,
                                int* __restrict__ cnt, int* __restrict__ csr_src,
                                _Float16* __restrict__ eas, int E, int N) {
  int i = blockIdx.x * 256 + threadIdx.x;
  if (i < 64) {
    if (i < 16) csr_src[E + N + i] = 0;
#pragma unroll
    for (int k = 0; k < 16; k++) eas[(size_t)(E + N + i) * 16 + k] = (_Float16)0.f;
  }
  if (i < E) {
    int d = dst0[i];
    int p = offs[d] + atomicAdd(&cnt[d], 1);
    csr_src[p] = src0[i];
    const float* s = ea + (size_t)i * 16;
    half8 h0, h1;
#pragma unroll
    for (int k = 0; k < 8; k++) { h0[k] = (_Float16)s[k]; h1[k] = (_Float16)s[k + 8]; }
    *(half8*)(eas + (size_t)p * 16) = h0;
    *(half8*)(eas + (size_t)p * 16 + 8) = h1;
  } else if (i < E + N) {
    int v = i - E;
    csr_src[offs[v] + deg[v]] = v;  // self-loop; attrs filled by loop_attr_kernel
  }
}

// self-loop attr = mean of real incoming slots (wave-per-node, coalesced)
__global__ void loop_attr_kernel(const int* __restrict__ offs, const int* __restrict__ deg,
                                 _Float16* __restrict__ eas, int N) {
  int wid = (blockIdx.x * 256 + threadIdx.x) >> 6;
  int l = threadIdx.x & 63;
  if (wid >= N) return;
  int b = offs[wid], dg = deg[wid];
  int k = l & 15, r = l >> 4;
  float s = 0.f;
  for (int j = r; j < dg; j += 4)
    s += (float)eas[(size_t)(b + j) * 16 + k];
  s += __shfl_xor(s, 16, 64);
  s += __shfl_xor(s, 32, 64);
  if (r == 0) eas[(size_t)(b + dg) * 16 + k] = (_Float16)(s / fmaxf((float)dg, 1.0f));
}

// ---------------- GEMM: [M,Nfull] = A[M,K]*BT[Nfull,K] + bias, split outputs ----------------
// r11: only delta vs the clean r8 run is the XCD-aware remap (index permutation
// only; same grid, same work, same addresses modulo block order).
template <bool RELU, bool OUT_F32>
__global__ __launch_bounds__(256) void gemm_f16(const _Float16* __restrict__ A,
                                                const _Float16* __restrict__ BT,
                                                const float* __restrict__ biasA,
                                                const float* __restrict__ biasB,
                                                void* __restrict__ CA,
                                                void* __restrict__ CB,
                                                int M, int K, int Nfull, int ldc) {
  __shared__ _Float16 As[128 * 32];
  __shared__ _Float16 Bs[128 * 32];
  int t = threadIdx.x;
  int gx = gridDim.x, gy = gridDim.y;
  int nwg = gx * gy;
  int bid2 = xcd_remap(blockIdx.y * gx + blockIdx.x, nwg);
  int m0 = (bid2 / gy) * 128;
  int n0 = (bid2 % gy) * 128;
  int l = t & 63, w = t >> 6;
  int wm = w & 1, wn = w >> 1;
  int lr = l & 15, lq = l >> 4;

  f32x4 acc[4][4];
#pragma unroll
  for (int i = 0; i < 4; i++)
#pragma unroll
    for (int j = 0; j < 4; j++) acc[i][j] = (f32x4){0.f, 0.f, 0.f, 0.f};

  int r0 = w * 32 + (l >> 2);
  int cb = (l & 3) * 8;
  const _Float16* Ap = A + (size_t)(m0 + r0) * K + cb;
  const _Float16* Bp = BT + (size_t)(n0 + r0) * K + cb;
  _Float16* AsW = As + w * 32 * 32;
  _Float16* BsW = Bs + w * 32 * 32;

  for (int kk = 0; kk < K; kk += 32) {
    GLOAD_LDS16(Ap, AsW);
    GLOAD_LDS16(Ap + (size_t)16 * K, AsW + 16 * 32);
    GLOAD_LDS16(Bp, BsW);
    GLOAD_LDS16(Bp + (size_t)16 * K, BsW + 16 * 32);
    Ap += 32; Bp += 32;
    __syncthreads();
    half8 af[4], bf[4];
#pragma unroll
    for (int mi = 0; mi < 4; mi++) af[mi] = *(const half8*)&As[(wm * 64 + mi * 16 + lr) * 32 + lq * 8];
#pragma unroll
    for (int ni = 0; ni < 4; ni++) bf[ni] = *(const half8*)&Bs[(wn * 64 + ni * 16 + lr) * 32 + lq * 8];
#pragma unroll
    for (int mi = 0; mi < 4; mi++)
#pragma unroll
      for (int ni = 0; ni < 4; ni++)
        acc[mi][ni] = __builtin_amdgcn_mfma_f32_16x16x32_f16(af[mi], bf[ni], acc[mi][ni], 0, 0, 0);
    __syncthreads();
  }

#pragma unroll
  for (int ni = 0; ni < 4; ni++) {
    int col = n0 + wn * 64 + ni * 16 + lr;
    if (col >= Nfull) continue;
    float bv = (col < 512) ? biasA[col] : biasB[col - 512];
    void* Cx = (col < 512) ? CA : CB;
    int cc = (col < 512) ? col : col - 512;
#pragma unroll
    for (int mi = 0; mi < 4; mi++) {
#pragma unroll
      for (int r = 0; r < 4; r++) {
        int row = m0 + wm * 64 + mi * 16 + lq * 4 + r;
        if (row >= M) continue;
        float v = acc[mi][ni][r] + bv;
        if (RELU) v = fmaxf(v, 0.f);
        if (OUT_F32) ((float*)Cx)[(size_t)row * ldc + cc] = v;
        else ((_Float16*)Cx)[(size_t)row * ldc + cc] = (_Float16)v;
      }
    }
  }
}

// ---------------- fused GATv2 edge pass (FROZEN r8 body: v4 loop, xl/xr split) ----------------
// r2-r8 law: the v4 inner loop at VGPR 116 is the only build under the 128-VGPR
// waves-halve cliff; every structural edit crossed it and cost 30-55%. FROZEN.

__device__ __forceinline__ void upd(float p, half8 xs, float& m, float& den, float acc[8]) {
  float mn = fmaxf(m, p);
  float sc = __expf(m - mn);
  float al = __expf(p - mn);
  den = den * sc + al;
#pragma unroll
  for (int jj = 0; jj < 8; jj++) acc[jj] = acc[jj] * sc + al * (float)xs[jj];
  m = mn;
}

__global__ __launch_bounds__(256) void gat_fused_kernel(
    const _Float16* __restrict__ xl,      // [Npad][512] source transforms
    const _Float16* __restrict__ xr,      // [Npad][512] target transforms
    const int* __restrict__ csr_src, const int* __restrict__ offs,
    const _Float16* __restrict__ eas,     // [EP+64][16] slot-ordered
    const _Float16* __restrict__ WeF,     // [32][16][16] MFMA-A fragment layout (v4)
    const _Float16* __restrict__ att16,   // [4][128] f16
    const float* __restrict__ bias,
    _Float16* __restrict__ hout, int N) {
  __shared__ _Float16 WeFL[16 * 512];     // 16KB: A-fragments
  __shared__ _Float16 EFs[4][16 * 512];   // 16KB/wave EF bounce buffer
  int t = threadIdx.x;
  int l = t & 63;
  int w = t >> 6;
  int h = l >> 4;
  int c0 = l * 8;
  int lr = l & 15, lq = l >> 4;

  {
    const _Float16* gW = WeF + w * 512 + l * 8;
    _Float16* lW = WeFL + w * 512;
#pragma unroll
    for (int p = 0; p < 4; p++) GLOAD_LDS16(gW + p * 2048, lW + p * 2048);
  }
  __syncthreads();

  _Float16* EFw = &EFs[w][0];
  half8 attv = *(const half8*)(att16 + h * 128 + lr * 8);
  const half2v lk = {(_Float16)0.2f, (_Float16)0.2f};

  int wid = blockIdx.x * 4 + w;
  int nw = gridDim.x * 4;

  for (int v0 = wid; v0 < N; v0 += nw) {
    int v = __builtin_amdgcn_readfirstlane(v0);
    int b = offs[v], e2 = offs[v + 1];
    half8 xrv = *(const half8*)(xr + (size_t)v * 512 + c0);

    // quad 0 indices + data (prologue, once per node)
    int s0 = csr_src[b], s1 = csr_src[b + 1], s2 = csr_src[b + 2], s3 = csr_src[b + 3];
    half8 xs0 = *(const half8*)(xl + (size_t)s0 * 512 + c0);
    half8 xs1 = *(const half8*)(xl + (size_t)s1 * 512 + c0);
    half8 xs2 = *(const half8*)(xl + (size_t)s2 * 512 + c0);
    half8 xs3 = *(const half8*)(xl + (size_t)s3 * 512 + c0);
    int t0 = csr_src[b + 4], t1 = csr_src[b + 5], t2 = csr_src[b + 6], t3 = csr_src[b + 7];
    half4 bfrag = *(const half4*)(eas + (size_t)(b + lr) * 16 + lq * 4);

    float m = -1e30f, den = 0.f;
    float acc[8];
#pragma unroll
    for (int j = 0; j < 8; j++) acc[j] = 0.f;

    for (int cs = b; cs < e2; cs += 16) {
      // ---- EF MFMA phase for slots [cs, cs+16) ----
#pragma unroll
      for (int g = 0; g < 32; g++) {
        half4 af = *(const half4*)(WeFL + g * 256 + lr * 16 + lq * 4);
        f32x4 d = __builtin_amdgcn_mfma_f32_16x16x16f16(af, bfrag, (f32x4){0.f, 0.f, 0.f, 0.f}, 0, 0, 0);
        half4 hd = {(_Float16)d[0], (_Float16)d[1], (_Float16)d[2], (_Float16)d[3]};
        int hi = (lr * 512 + g * 16 + lq * 4) ^ ((lr & 7) << 3);
        *(half4*)(EFw + hi) = hd;
      }
      // prefetch next chunk's ea fragment (eas padded by 64 slots)
      bfrag = *(const half4*)(eas + (size_t)(cs + 16 + lr) * 16 + lq * 4);

      int cse = min(cs + 16, e2);
      for (int j = cs; j < cse; j += 4) {
        // next quad's xs gathers (indices loaded last iteration)
        half8 nx0 = *(const half8*)(xl + (size_t)t0 * 512 + c0);
        half8 nx1 = *(const half8*)(xl + (size_t)t1 * 512 + c0);
        half8 nx2 = *(const half8*)(xl + (size_t)t2 * 512 + c0);
        half8 nx3 = *(const half8*)(xl + (size_t)t3 * 512 + c0);
        // indices for quad j+8 (2 ahead); csr_src padded +16
        int u0 = csr_src[j + 8], u1 = csr_src[j + 9], u2 = csr_src[j + 10], u3 = csr_src[j + 11];

        // EF rows for this quad (conflict-free swizzled b128)
        int si = j - cs;
        half8 ef0 = *(const half8*)(EFw + (((si    ) * 512 + l * 8) ^ (((si    ) & 7) << 3)));
        half8 ef1 = *(const half8*)(EFw + (((si + 1) * 512 + l * 8) ^ (((si + 1) & 7) << 3)));
        half8 ef2 = *(const half8*)(EFw + (((si + 2) * 512 + l * 8) ^ (((si + 2) & 7) << 3)));
        half8 ef3 = *(const half8*)(EFw + (((si + 3) * 512 + l * 8) ^ (((si + 3) & 7) << 3)));

        float p0 = 0.f, p1 = 0.f, p2 = 0.f, p3 = 0.f;
#pragma unroll
        for (int p = 0; p < 4; p++) {
          half2v xrp = H2(xrv, p);
          half2v ap = H2(attv, p);
          half2v v0v = H2(xs0, p) + xrp + H2(ef0, p);
          half2v v1v = H2(xs1, p) + xrp + H2(ef1, p);
          half2v v2v = H2(xs2, p) + xrp + H2(ef2, p);
          half2v v3v = H2(xs3, p) + xrp + H2(ef3, p);
          v0v = __builtin_elementwise_max(v0v, v0v * lk);
          v1v = __builtin_elementwise_max(v1v, v1v * lk);
          v2v = __builtin_elementwise_max(v2v, v2v * lk);
          v3v = __builtin_elementwise_max(v3v, v3v * lk);
          p0 = FDOT2(v0v, ap, p0);
          p1 = FDOT2(v1v, ap, p1);
          p2 = FDOT2(v2v, ap, p2);
          p3 = FDOT2(v3v, ap, p3);
        }
        p0 = rowsum16(p0); p1 = rowsum16(p1); p2 = rowsum16(p2); p3 = rowsum16(p3);

        upd(p0, xs0, m, den, acc);
        if (j + 1 < e2) upd(p1, xs1, m, den, acc);
        if (j + 2 < e2) upd(p2, xs2, m, den, acc);
        if (j + 3 < e2) upd(p3, xs3, m, den, acc);

        // rotate pipeline
        xs0 = nx0; xs1 = nx1; xs2 = nx2; xs3 = nx3;
        t0 = u0; t1 = u1; t2 = u2; t3 = u3;
      }
    }
    float rd = 1.f / (den + 1e-16f);
    half8 o;
#pragma unroll
    for (int jj = 0; jj < 8; jj++) o[jj] = (_Float16)(fmaf(acc[jj], rd, bias[c0 + jj]));
    *(half8*)(hout + (size_t)v * 512 + c0) = o;
  }
}

// ---------------- launcher ----------------

extern "C" void kernel_launch(void* const* d_in, const int* in_sizes, int n_in,
                              void* d_out, int out_size, void* d_ws, size_t ws_size,
                              hipStream_t stream) {
  (void)n_in; (void)out_size; (void)ws_size;
  const float* x    = (const float*)d_in[0];
  const int*   ei   = (const int*)d_in[1];
  const float* ea   = (const float*)d_in[2];
  const float* Wl1  = (const float*)d_in[3];
  const float* bl1  = (const float*)d_in[4];
  const float* Wr1  = (const float*)d_in[5];
  const float* br1  = (const float*)d_in[6];
  const float* We1  = (const float*)d_in[7];
  const float* att1 = (const float*)d_in[8];
  const float* bias1= (const float*)d_in[9];
  const float* Wl2  = (const float*)d_in[10];
  const float* bl2  = (const float*)d_in[11];
  const float* Wr2  = (const float*)d_in[12];
  const float* br2  = (const float*)d_in[13];
  const float* We2  = (const float*)d_in[14];
  const float* att2 = (const float*)d_in[15];
  const float* bias2= (const float*)d_in[16];
  const float* Wd1  = (const float*)d_in[17];
  const float* bd1  = (const float*)d_in[18];
  const float* Wd2  = (const float*)d_in[19];
  const float* bd2  = (const float*)d_in[20];

  const int N = in_sizes[0] / 128;
  const int E = in_sizes[1] / 2;
  const int EP = E + N;
  const int Npad = (N + 127) & ~127;
  const int* src0 = ei;
  const int* dst0 = ei + E;

  char* ws = (char*)d_ws;
  size_t off = 0;
  auto alloc = [&](size_t bytes) -> void* {
    void* p = ws + off;
    off += (bytes + 255) & ~(size_t)255;
    return p;
  };

  int*   deg    = (int*)alloc((size_t)N * 8);
  int*   cnt    = deg + N;
  int*   offs   = (int*)alloc(((size_t)N + 1) * 4);
  int*   csr_src= (int*)alloc(((size_t)EP + 16) * 4);
  _Float16* eas = (_Float16*)alloc(((size_t)EP + 64) * 16 * 2);
  _Float16* x16   = (_Float16*)alloc((size_t)Npad * 128 * 2);
  _Float16* xl16  = (_Float16*)alloc((size_t)Npad * 512 * 2);
  _Float16* xr16  = (_Float16*)alloc((size_t)Npad * 512 * 2);
  _Float16* h16   = (_Float16*)alloc((size_t)Npad * 512 * 2);
  _Float16* WlrT1 = (_Float16*)alloc(1024 * 128 * 2);
  _Float16* WlrT2 = (_Float16*)alloc(1024 * 512 * 2);
  _Float16* WdT1  = (_Float16*)alloc(512 * 512 * 2);
  _Float16* WdT2  = (_Float16*)alloc(128 * 512 * 2);
  _Float16* WeF1  = (_Float16*)alloc(16 * 512 * 2);
  _Float16* WeF2  = (_Float16*)alloc(16 * 512 * 2);
  _Float16* att16_1 = (_Float16*)alloc(512 * 2);
  _Float16* att16_2 = (_Float16*)alloc(512 * 2);
  _Float16* t16   = xl16;  // decoder hidden reuses xl buffer (dead by then)

  hipMemsetAsync(deg, 0, (size_t)N * 8, stream);

  // mega prep (also does the degree histogram)
  int nx = N * 128;
  int prep_base = nx + 1024 * 128 + 1024 * 512 + 512 * 512 + 64 * 512
                + 512 * 16 + 512 * 16 + 512 + 512;
  int prep_total = prep_base + E;
  prep_kernel<<<(prep_total + 255) / 256, 256, 0, stream>>>(
      x, x16, nx, Wl1, Wr1, WlrT1, Wl2, Wr2, WlrT2,
      Wd1, WdT1, Wd2, WdT2, We1, WeF1, We2, WeF2,
      att1, att16_1, att2, att16_2, dst0, deg, E);

  // CSR build (csr_fill also writes slot-ordered edge attrs)
  int g;
  scan_kernel<<<1, 1024, 0, stream>>>(deg, offs, N);
  g = (EP + 255) / 256;
  csr_fill_kernel<<<g, 256, 0, stream>>>(src0, dst0, ea, offs, deg, cnt, csr_src, eas, E, N);
  g = (N * 64 + 255) / 256;
  loop_attr_kernel<<<g, 256, 0, stream>>>(offs, deg, eas, N);

  dim3 gb(256);
  dim3 ggm((N + 127) / 128, 8);
  dim3 ggd((N + 127) / 128, 4);
  dim3 ggo((N + 127) / 128, 1);

  const int FGRID = 2048;

  // ---- GAT layer 1 ----
  gemm_f16<false, false><<<ggm, gb, 0, stream>>>(x16, WlrT1, bl1, br1, xl16, xr16, N, 128, 1024, 512);
  gat_fused_kernel<<<FGRID, 256, 0, stream>>>(xl16, xr16, csr_src, offs, eas, WeF1, att16_1, bias1, h16, N);

  // ---- GAT layer 2 ----
  gemm_f16<false, false><<<ggm, gb, 0, stream>>>(h16, WlrT2, bl2, br2, xl16, xr16, N, 512, 1024, 512);
  gat_fused_kernel<<<FGRID, 256, 0, stream>>>(xl16, xr16, csr_src, offs, eas, WeF2, att16_2, bias2, h16, N);

  // ---- decoder ----
  gemm_f16<true, false><<<ggd, gb, 0, stream>>>(h16, WdT1, bd1, bd1, t16, t16, N, 512, 512, 512);
  gemm_f16<false, true><<<ggo, gb, 0, stream>>>(t16, WdT2, bd2, bd2, d_out, d_out, N, 512, 64, 64);
}

// Round 12
// 449.336 us; speedup vs baseline: 1.2584x; 1.0911x over previous
//
#include <hip/hip_runtime.h>
#include <hip/hip_fp16.h>

typedef _Float16 half8 __attribute__((ext_vector_type(8)));
typedef _Float16 half4 __attribute__((ext_vector_type(4)));
typedef _Float16 half2v __attribute__((ext_vector_type(2)));
typedef float f32x4 __attribute__((ext_vector_type(4)));

#if __has_builtin(__builtin_amdgcn_fdot2)
#define FDOT2(a, b, c) __builtin_amdgcn_fdot2((a), (b), (c), false)
#else
static __device__ __forceinline__ float FDOT2(half2v a, half2v b, float c) {
  return (float)a[0] * (float)b[0] + (float)a[1] * (float)b[1] + c;
}
#endif
#define H2(v8, p) ((half2v){(v8)[2 * (p)], (v8)[2 * (p) + 1]})

// async global->LDS, 16B per lane; dest = lds base (wave-uniform) + lane*16
#define GLOAD_LDS16(gp, lp)                                                        \
  __builtin_amdgcn_global_load_lds(                                                \
      (const __attribute__((address_space(1))) void*)(gp),                         \
      (__attribute__((address_space(3))) void*)(lp), 16, 0, 0)

// 16-lane all-reduce via DPP rotate-accumulate: 4 VALU ops, no LDS pipe.
template <int CTRL>
__device__ __forceinline__ float dpp_add16(float x) {
  int y = __builtin_amdgcn_update_dpp(0, __float_as_int(x), CTRL, 0xf, 0xf, true);
  return x + __int_as_float(y);
}
__device__ __forceinline__ float rowsum16(float x) {
  x = dpp_add16<0x128>(x);  // row_ror:8
  x = dpp_add16<0x124>(x);  // row_ror:4
  x = dpp_add16<0x122>(x);  // row_ror:2
  x = dpp_add16<0x121>(x);  // row_ror:1
  return x;
}

// XCD-aware bijective block remap (m204): cluster blocks sharing an A-panel on
// one XCD so its 4MB L2 holds ~20 A-panels (2.5MB) + the whole B panel (<=1MB).
// r11 measured: -12.8us total.
__device__ __forceinline__ int xcd_remap(int bid, int nwg) {
  int xcd = bid & 7, idx = bid >> 3;
  int q8 = nwg >> 3, r8 = nwg & 7;
  return (xcd < r8) ? (xcd * (q8 + 1) + idx)
                    : (r8 * (q8 + 1) + (xcd - r8) * q8 + idx);
}

// ---------------- mega prep kernel ----------------
// WeF layout: v4's [32 groups][16 ch][16 k] (r6 lesson: lane-linear relayout
// perturbs gat regalloc over the 128-VGPR cliff; keep v4).
__global__ void prep_kernel(const float* __restrict__ x, _Float16* __restrict__ x16, int nx,
                            const float* __restrict__ Wl1, const float* __restrict__ Wr1,
                            _Float16* __restrict__ WlrT1,
                            const float* __restrict__ Wl2, const float* __restrict__ Wr2,
                            _Float16* __restrict__ WlrT2,
                            const float* __restrict__ Wd1, _Float16* __restrict__ WdT1,
                            const float* __restrict__ Wd2, _Float16* __restrict__ WdT2,
                            const float* __restrict__ We1, _Float16* __restrict__ WeF1,
                            const float* __restrict__ We2, _Float16* __restrict__ WeF2,
                            const float* __restrict__ att1, _Float16* __restrict__ att16_1,
                            const float* __restrict__ att2, _Float16* __restrict__ att16_2,
                            const int* __restrict__ dst0, int* __restrict__ deg, int E) {
  int i = blockIdx.x * 256 + threadIdx.x;
  if (i < nx) { x16[i] = (_Float16)x[i]; return; }
  i -= nx;
  if (i < 1024 * 128) {
    int n = i >> 7, k = i & 127;
    float v = (n < 512) ? Wl1[(size_t)k * 512 + n] : Wr1[(size_t)k * 512 + (n - 512)];
    WlrT1[i] = (_Float16)v; return;
  }
  i -= 1024 * 128;
  if (i < 1024 * 512) {
    int n = i >> 9, k = i & 511;
    float v = (n < 512) ? Wl2[(size_t)k * 512 + n] : Wr2[(size_t)k * 512 + (n - 512)];
    WlrT2[i] = (_Float16)v; return;
  }
  i -= 1024 * 512;
  if (i < 512 * 512) { int n = i >> 9, k = i & 511; WdT1[i] = (_Float16)Wd1[(size_t)k * 512 + n]; return; }
  i -= 512 * 512;
  if (i < 64 * 512)  { int n = i >> 9, k = i & 511; WdT2[i] = (_Float16)Wd2[(size_t)k * 64 + n]; return; }
  i -= 64 * 512;
  if (i < 512 * 16) {  // WeF1[g][c][k] = We1[k][g*16+c]  (v4 layout)
    int k = i & 15, c = (i >> 4) & 15, g = i >> 8;
    WeF1[i] = (_Float16)We1[(size_t)k * 512 + g * 16 + c]; return;
  }
  i -= 512 * 16;
  if (i < 512 * 16) {
    int k = i & 15, c = (i >> 4) & 15, g = i >> 8;
    WeF2[i] = (_Float16)We2[(size_t)k * 512 + g * 16 + c]; return;
  }
  i -= 512 * 16;
  if (i < 512)       { att16_1[i] = (_Float16)att1[i]; return; }
  i -= 512;
  if (i < 512)       { att16_2[i] = (_Float16)att2[i]; return; }
  i -= 512;
  if (i < E)         { atomicAdd(&deg[dst0[i]], 1); return; }
}

// ---------------- CSR build ----------------
__global__ __launch_bounds__(1024) void scan_kernel(const int* __restrict__ deg, int* __restrict__ offs, int N) {
  __shared__ int part[1024];
  int t = threadIdx.x;
  int chunk = (N + 1023) / 1024;
  int b = t * chunk, e = min(b + chunk, N);
  int s = 0;
  for (int i = b; i < e; i++) s += deg[i] + 1;
  part[t] = s;
  __syncthreads();
  for (int off = 1; off < 1024; off <<= 1) {
    int v = (t >= off) ? part[t - off] : 0;
    __syncthreads();
    part[t] += v;
    __syncthreads();
  }
  int run = (t == 0) ? 0 : part[t - 1];
  for (int i = b; i < e; i++) { offs[i] = run; run += deg[i] + 1; }
  if (t == 1023) offs[N] = part[1023];
}

// scatter src + slot-ordered edge attr (f16) in one pass; pads zeroed 64 slots
__global__ void csr_fill_kernel(const int* __restrict__ src0, const int* __restrict__ dst0,
                                const float* __restrict__ ea,
                                const int* __restrict__ offs, const int* __restrict__ deg,
                                int* __restrict__ cnt, int* __restrict__ csr_src,
                                _Float16* __restrict__ eas, int E, int N) {
  int i = blockIdx.x * 256 + threadIdx.x;
  if (i < 64) {
    if (i < 16) csr_src[E + N + i] = 0;
#pragma unroll
    for (int k = 0; k < 16; k++) eas[(size_t)(E + N + i) * 16 + k] = (_Float16)0.f;
  }
  if (i < E) {
    int d = dst0[i];
    int p = offs[d] + atomicAdd(&cnt[d], 1);
    csr_src[p] = src0[i];
    const float* s = ea + (size_t)i * 16;
    half8 h0, h1;
#pragma unroll
    for (int k = 0; k < 8; k++) { h0[k] = (_Float16)s[k]; h1[k] = (_Float16)s[k + 8]; }
    *(half8*)(eas + (size_t)p * 16) = h0;
    *(half8*)(eas + (size_t)p * 16 + 8) = h1;
  } else if (i < E + N) {
    int v = i - E;
    csr_src[offs[v] + deg[v]] = v;  // self-loop; attrs filled by loop_attr_kernel
  }
}

// self-loop attr = mean of real incoming slots (wave-per-node, coalesced)
__global__ void loop_attr_kernel(const int* __restrict__ offs, const int* __restrict__ deg,
                                 _Float16* __restrict__ eas, int N) {
  int wid = (blockIdx.x * 256 + threadIdx.x) >> 6;
  int l = threadIdx.x & 63;
  if (wid >= N) return;
  int b = offs[wid], dg = deg[wid];
  int k = l & 15, r = l >> 4;
  float s = 0.f;
  for (int j = r; j < dg; j += 4)
    s += (float)eas[(size_t)(b + j) * 16 + k];
  s += __shfl_xor(s, 16, 64);
  s += __shfl_xor(s, 32, 64);
  if (r == 0) eas[(size_t)(b + dg) * 16 + k] = (_Float16)(s / fmaxf((float)dg, 1.0f));
}

// ---------------- GEMM: [M,Nfull] = A[M,K]*BT[Nfull,K] + bias, split outputs ----------------
// r12: f16 epilogue bounces each wave's 64x64 C-tile through LDS (reusing the
// dead As/Bs staging space) so global stores are 8x half8 (16B) per thread
// instead of 64x 2B scalar stores. f32 path (dec2, 64 cols) keeps scalar.
template <bool RELU, bool OUT_F32>
__global__ __launch_bounds__(256) void gemm_f16(const _Float16* __restrict__ A,
                                                const _Float16* __restrict__ BT,
                                                const float* __restrict__ biasA,
                                                const float* __restrict__ biasB,
                                                void* __restrict__ CA,
                                                void* __restrict__ CB,
                                                int M, int K, int Nfull, int ldc) {
  __shared__ _Float16 SBUF[4 * 64 * 64];      // 32KB union: [As 8KB | Bs 8KB] / C-bounce 4x8KB
  _Float16* As = SBUF;                        // [128][32]
  _Float16* Bs = SBUF + 4096;                 // [128][32]
  int t = threadIdx.x;
  int gx = gridDim.x, gy = gridDim.y;
  int nwg = gx * gy;
  int bid2 = xcd_remap(blockIdx.y * gx + blockIdx.x, nwg);
  int m0 = (bid2 / gy) * 128;
  int n0 = (bid2 % gy) * 128;
  int l = t & 63, w = t >> 6;
  int wm = w & 1, wn = w >> 1;
  int lr = l & 15, lq = l >> 4;

  f32x4 acc[4][4];
#pragma unroll
  for (int i = 0; i < 4; i++)
#pragma unroll
    for (int j = 0; j < 4; j++) acc[i][j] = (f32x4){0.f, 0.f, 0.f, 0.f};

  int r0 = w * 32 + (l >> 2);
  int cb = (l & 3) * 8;
  const _Float16* Ap = A + (size_t)(m0 + r0) * K + cb;
  const _Float16* Bp = BT + (size_t)(n0 + r0) * K + cb;
  _Float16* AsW = As + w * 32 * 32;
  _Float16* BsW = Bs + w * 32 * 32;

  for (int kk = 0; kk < K; kk += 32) {
    GLOAD_LDS16(Ap, AsW);
    GLOAD_LDS16(Ap + (size_t)16 * K, AsW + 16 * 32);
    GLOAD_LDS16(Bp, BsW);
    GLOAD_LDS16(Bp + (size_t)16 * K, BsW + 16 * 32);
    Ap += 32; Bp += 32;
    __syncthreads();
    half8 af[4], bf[4];
#pragma unroll
    for (int mi = 0; mi < 4; mi++) af[mi] = *(const half8*)&As[(wm * 64 + mi * 16 + lr) * 32 + lq * 8];
#pragma unroll
    for (int ni = 0; ni < 4; ni++) bf[ni] = *(const half8*)&Bs[(wn * 64 + ni * 16 + lr) * 32 + lq * 8];
#pragma unroll
    for (int mi = 0; mi < 4; mi++)
#pragma unroll
      for (int ni = 0; ni < 4; ni++)
        acc[mi][ni] = __builtin_amdgcn_mfma_f32_16x16x32_f16(af[mi], bf[ni], acc[mi][ni], 0, 0, 0);
    __syncthreads();
  }

  if (!OUT_F32) {
    // ---- LDS-bounce f16 epilogue ----
    int colbase = n0 + wn * 64;               // wave-uniform; 64-col range never straddles 512
    const float* biasP = (colbase < 512) ? biasA : biasB;
    int cb0 = (colbase < 512) ? colbase : colbase - 512;
    _Float16* Cx = (_Float16*)((colbase < 512) ? CA : CB);
    _Float16* Cw = SBUF + w * 4096;           // this wave's 64x64 tile
#pragma unroll
    for (int ni = 0; ni < 4; ni++) {
      float bv = biasP[cb0 + ni * 16 + lr];
#pragma unroll
      for (int mi = 0; mi < 4; mi++) {
#pragma unroll
        for (int r = 0; r < 4; r++) {
          float v = acc[mi][ni][r] + bv;
          if (RELU) v = fmaxf(v, 0.f);
          Cw[(mi * 16 + lq * 4 + r) * 64 + ni * 16 + lr] = (_Float16)v;
        }
      }
    }
    __syncthreads();  // cross-lane LDS handoff (write phase -> read phase)
    int lrow = l >> 3, lcb = (l & 7) * 8;
#pragma unroll
    for (int ps = 0; ps < 8; ps++) {
      int row = m0 + wm * 64 + ps * 8 + lrow;
      half8 vv = *(const half8*)(Cw + (ps * 8 + lrow) * 64 + lcb);
      if (row < M) *(half8*)(Cx + (size_t)row * ldc + cb0 + lcb) = vv;
    }
  } else {
    // ---- scalar f32 epilogue (dec2 only: Nfull=64, tiny) ----
#pragma unroll
    for (int ni = 0; ni < 4; ni++) {
      int col = n0 + wn * 64 + ni * 16 + lr;
      if (col >= Nfull) continue;
      float bv = (col < 512) ? biasA[col] : biasB[col - 512];
      float* Cx = (float*)((col < 512) ? CA : CB);
      int cc = (col < 512) ? col : col - 512;
#pragma unroll
      for (int mi = 0; mi < 4; mi++) {
#pragma unroll
        for (int r = 0; r < 4; r++) {
          int row = m0 + wm * 64 + mi * 16 + lq * 4 + r;
          if (row >= M) continue;
          float v = acc[mi][ni][r] + bv;
          if (RELU) v = fmaxf(v, 0.f);
          Cx[(size_t)row * ldc + cc] = v;
        }
      }
    }
  }
}

// ---------------- fused GATv2 edge pass (FROZEN r8 body: v4 loop, xl/xr split) ----------------
// r2-r8 law: the v4 inner loop at VGPR 116 is the only build under the 128-VGPR
// waves-halve cliff; every structural edit crossed it and cost 30-55%. FROZEN.

__device__ __forceinline__ void upd(float p, half8 xs, float& m, float& den, float acc[8]) {
  float mn = fmaxf(m, p);
  float sc = __expf(m - mn);
  float al = __expf(p - mn);
  den = den * sc + al;
#pragma unroll
  for (int jj = 0; jj < 8; jj++) acc[jj] = acc[jj] * sc + al * (float)xs[jj];
  m = mn;
}

__global__ __launch_bounds__(256) void gat_fused_kernel(
    const _Float16* __restrict__ xl,      // [Npad][512] source transforms
    const _Float16* __restrict__ xr,      // [Npad][512] target transforms
    const int* __restrict__ csr_src, const int* __restrict__ offs,
    const _Float16* __restrict__ eas,     // [EP+64][16] slot-ordered
    const _Float16* __restrict__ WeF,     // [32][16][16] MFMA-A fragment layout (v4)
    const _Float16* __restrict__ att16,   // [4][128] f16
    const float* __restrict__ bias,
    _Float16* __restrict__ hout, int N) {
  __shared__ _Float16 WeFL[16 * 512];     // 16KB: A-fragments
  __shared__ _Float16 EFs[4][16 * 512];   // 16KB/wave EF bounce buffer
  int t = threadIdx.x;
  int l = t & 63;
  int w = t >> 6;
  int h = l >> 4;
  int c0 = l * 8;
  int lr = l & 15, lq = l >> 4;

  {
    const _Float16* gW = WeF + w * 512 + l * 8;
    _Float16* lW = WeFL + w * 512;
#pragma unroll
    for (int p = 0; p < 4; p++) GLOAD_LDS16(gW + p * 2048, lW + p * 2048);
  }
  __syncthreads();

  _Float16* EFw = &EFs[w][0];
  half8 attv = *(const half8*)(att16 + h * 128 + lr * 8);
  const half2v lk = {(_Float16)0.2f, (_Float16)0.2f};

  int wid = blockIdx.x * 4 + w;
  int nw = gridDim.x * 4;

  for (int v0 = wid; v0 < N; v0 += nw) {
    int v = __builtin_amdgcn_readfirstlane(v0);
    int b = offs[v], e2 = offs[v + 1];
    half8 xrv = *(const half8*)(xr + (size_t)v * 512 + c0);

    // quad 0 indices + data (prologue, once per node)
    int s0 = csr_src[b], s1 = csr_src[b + 1], s2 = csr_src[b + 2], s3 = csr_src[b + 3];
    half8 xs0 = *(const half8*)(xl + (size_t)s0 * 512 + c0);
    half8 xs1 = *(const half8*)(xl + (size_t)s1 * 512 + c0);
    half8 xs2 = *(const half8*)(xl + (size_t)s2 * 512 + c0);
    half8 xs3 = *(const half8*)(xl + (size_t)s3 * 512 + c0);
    int t0 = csr_src[b + 4], t1 = csr_src[b + 5], t2 = csr_src[b + 6], t3 = csr_src[b + 7];
    half4 bfrag = *(const half4*)(eas + (size_t)(b + lr) * 16 + lq * 4);

    float m = -1e30f, den = 0.f;
    float acc[8];
#pragma unroll
    for (int j = 0; j < 8; j++) acc[j] = 0.f;

    for (int cs = b; cs < e2; cs += 16) {
      // ---- EF MFMA phase for slots [cs, cs+16) ----
#pragma unroll
      for (int g = 0; g < 32; g++) {
        half4 af = *(const half4*)(WeFL + g * 256 + lr * 16 + lq * 4);
        f32x4 d = __builtin_amdgcn_mfma_f32_16x16x16f16(af, bfrag, (f32x4){0.f, 0.f, 0.f, 0.f}, 0, 0, 0);
        half4 hd = {(_Float16)d[0], (_Float16)d[1], (_Float16)d[2], (_Float16)d[3]};
        int hi = (lr * 512 + g * 16 + lq * 4) ^ ((lr & 7) << 3);
        *(half4*)(EFw + hi) = hd;
      }
      // prefetch next chunk's ea fragment (eas padded by 64 slots)
      bfrag = *(const half4*)(eas + (size_t)(cs + 16 + lr) * 16 + lq * 4);

      int cse = min(cs + 16, e2);
      for (int j = cs; j < cse; j += 4) {
        // next quad's xs gathers (indices loaded last iteration)
        half8 nx0 = *(const half8*)(xl + (size_t)t0 * 512 + c0);
        half8 nx1 = *(const half8*)(xl + (size_t)t1 * 512 + c0);
        half8 nx2 = *(const half8*)(xl + (size_t)t2 * 512 + c0);
        half8 nx3 = *(const half8*)(xl + (size_t)t3 * 512 + c0);
        // indices for quad j+8 (2 ahead); csr_src padded +16
        int u0 = csr_src[j + 8], u1 = csr_src[j + 9], u2 = csr_src[j + 10], u3 = csr_src[j + 11];

        // EF rows for this quad (conflict-free swizzled b128)
        int si = j - cs;
        half8 ef0 = *(const half8*)(EFw + (((si    ) * 512 + l * 8) ^ (((si    ) & 7) << 3)));
        half8 ef1 = *(const half8*)(EFw + (((si + 1) * 512 + l * 8) ^ (((si + 1) & 7) << 3)));
        half8 ef2 = *(const half8*)(EFw + (((si + 2) * 512 + l * 8) ^ (((si + 2) & 7) << 3)));
        half8 ef3 = *(const half8*)(EFw + (((si + 3) * 512 + l * 8) ^ (((si + 3) & 7) << 3)));

        float p0 = 0.f, p1 = 0.f, p2 = 0.f, p3 = 0.f;
#pragma unroll
        for (int p = 0; p < 4; p++) {
          half2v xrp = H2(xrv, p);
          half2v ap = H2(attv, p);
          half2v v0v = H2(xs0, p) + xrp + H2(ef0, p);
          half2v v1v = H2(xs1, p) + xrp + H2(ef1, p);
          half2v v2v = H2(xs2, p) + xrp + H2(ef2, p);
          half2v v3v = H2(xs3, p) + xrp + H2(ef3, p);
          v0v = __builtin_elementwise_max(v0v, v0v * lk);
          v1v = __builtin_elementwise_max(v1v, v1v * lk);
          v2v = __builtin_elementwise_max(v2v, v2v * lk);
          v3v = __builtin_elementwise_max(v3v, v3v * lk);
          p0 = FDOT2(v0v, ap, p0);
          p1 = FDOT2(v1v, ap, p1);
          p2 = FDOT2(v2v, ap, p2);
          p3 = FDOT2(v3v, ap, p3);
        }
        p0 = rowsum16(p0); p1 = rowsum16(p1); p2 = rowsum16(p2); p3 = rowsum16(p3);

        upd(p0, xs0, m, den, acc);
        if (j + 1 < e2) upd(p1, xs1, m, den, acc);
        if (j + 2 < e2) upd(p2, xs2, m, den, acc);
        if (j + 3 < e2) upd(p3, xs3, m, den, acc);

        // rotate pipeline
        xs0 = nx0; xs1 = nx1; xs2 = nx2; xs3 = nx3;
        t0 = u0; t1 = u1; t2 = u2; t3 = u3;
      }
    }
    float rd = 1.f / (den + 1e-16f);
    half8 o;
#pragma unroll
    for (int jj = 0; jj < 8; jj++) o[jj] = (_Float16)(fmaf(acc[jj], rd, bias[c0 + jj]));
    *(half8*)(hout + (size_t)v * 512 + c0) = o;
  }
}

// ---------------- launcher ----------------

extern "C" void kernel_launch(void* const* d_in, const int* in_sizes, int n_in,
                              void* d_out, int out_size, void* d_ws, size_t ws_size,
                              hipStream_t stream) {
  (void)n_in; (void)out_size; (void)ws_size;
  const float* x    = (const float*)d_in[0];
  const int*   ei   = (const int*)d_in[1];
  const float* ea   = (const float*)d_in[2];
  const float* Wl1  = (const float*)d_in[3];
  const float* bl1  = (const float*)d_in[4];
  const float* Wr1  = (const float*)d_in[5];
  const float* br1  = (const float*)d_in[6];
  const float* We1  = (const float*)d_in[7];
  const float* att1 = (const float*)d_in[8];
  const float* bias1= (const float*)d_in[9];
  const float* Wl2  = (const float*)d_in[10];
  const float* bl2  = (const float*)d_in[11];
  const float* Wr2  = (const float*)d_in[12];
  const float* br2  = (const float*)d_in[13];
  const float* We2  = (const float*)d_in[14];
  const float* att2 = (const float*)d_in[15];
  const float* bias2= (const float*)d_in[16];
  const float* Wd1  = (const float*)d_in[17];
  const float* bd1  = (const float*)d_in[18];
  const float* Wd2  = (const float*)d_in[19];
  const float* bd2  = (const float*)d_in[20];

  const int N = in_sizes[0] / 128;
  const int E = in_sizes[1] / 2;
  const int EP = E + N;
  const int Npad = (N + 127) & ~127;
  const int* src0 = ei;
  const int* dst0 = ei + E;

  char* ws = (char*)d_ws;
  size_t off = 0;
  auto alloc = [&](size_t bytes) -> void* {
    void* p = ws + off;
    off += (bytes + 255) & ~(size_t)255;
    return p;
  };

  int*   deg    = (int*)alloc((size_t)N * 8);
  int*   cnt    = deg + N;
  int*   offs   = (int*)alloc(((size_t)N + 1) * 4);
  int*   csr_src= (int*)alloc(((size_t)EP + 16) * 4);
  _Float16* eas = (_Float16*)alloc(((size_t)EP + 64) * 16 * 2);
  _Float16* x16   = (_Float16*)alloc((size_t)Npad * 128 * 2);
  _Float16* xl16  = (_Float16*)alloc((size_t)Npad * 512 * 2);
  _Float16* xr16  = (_Float16*)alloc((size_t)Npad * 512 * 2);
  _Float16* h16   = (_Float16*)alloc((size_t)Npad * 512 * 2);
  _Float16* WlrT1 = (_Float16*)alloc(1024 * 128 * 2);
  _Float16* WlrT2 = (_Float16*)alloc(1024 * 512 * 2);
  _Float16* WdT1  = (_Float16*)alloc(512 * 512 * 2);
  _Float16* WdT2  = (_Float16*)alloc(128 * 512 * 2);
  _Float16* WeF1  = (_Float16*)alloc(16 * 512 * 2);
  _Float16* WeF2  = (_Float16*)alloc(16 * 512 * 2);
  _Float16* att16_1 = (_Float16*)alloc(512 * 2);
  _Float16* att16_2 = (_Float16*)alloc(512 * 2);
  _Float16* t16   = xl16;  // decoder hidden reuses xl buffer (dead by then)

  hipMemsetAsync(deg, 0, (size_t)N * 8, stream);

  // mega prep (also does the degree histogram)
  int nx = N * 128;
  int prep_base = nx + 1024 * 128 + 1024 * 512 + 512 * 512 + 64 * 512
                + 512 * 16 + 512 * 16 + 512 + 512;
  int prep_total = prep_base + E;
  prep_kernel<<<(prep_total + 255) / 256, 256, 0, stream>>>(
      x, x16, nx, Wl1, Wr1, WlrT1, Wl2, Wr2, WlrT2,
      Wd1, WdT1, Wd2, WdT2, We1, WeF1, We2, WeF2,
      att1, att16_1, att2, att16_2, dst0, deg, E);

  // CSR build (csr_fill also writes slot-ordered edge attrs)
  int g;
  scan_kernel<<<1, 1024, 0, stream>>>(deg, offs, N);
  g = (EP + 255) / 256;
  csr_fill_kernel<<<g, 256, 0, stream>>>(src0, dst0, ea, offs, deg, cnt, csr_src, eas, E, N);
  g = (N * 64 + 255) / 256;
  loop_attr_kernel<<<g, 256, 0, stream>>>(offs, deg, eas, N);

  dim3 gb(256);
  dim3 ggm((N + 127) / 128, 8);
  dim3 ggd((N + 127) / 128, 4);
  dim3 ggo((N + 127) / 128, 1);

  const int FGRID = 2048;

  // ---- GAT layer 1 ----
  gemm_f16<false, false><<<ggm, gb, 0, stream>>>(x16, WlrT1, bl1, br1, xl16, xr16, N, 128, 1024, 512);
  gat_fused_kernel<<<FGRID, 256, 0, stream>>>(xl16, xr16, csr_src, offs, eas, WeF1, att16_1, bias1, h16, N);

  // ---- GAT layer 2 ----
  gemm_f16<false, false><<<ggm, gb, 0, stream>>>(h16, WlrT2, bl2, br2, xl16, xr16, N, 512, 1024, 512);
  gat_fused_kernel<<<FGRID, 256, 0, stream>>>(xl16, xr16, csr_src, offs, eas, WeF2, att16_2, bias2, h16, N);

  // ---- decoder ----
  gemm_f16<true, false><<<ggd, gb, 0, stream>>>(h16, WdT1, bd1, bd1, t16, t16, N, 512, 512, 512);
  gemm_f16<false, true><<<ggo, gb, 0, stream>>>(t16, WdT2, bd2, bd2, d_out, d_out, N, 512, 64, 64);
}